// Round 20
// baseline (402.867 us; speedup 1.0000x reference)
//
#include <hip/hip_runtime.h>
#include <stdint.h>

typedef unsigned short u16;
typedef __bf16 bf16x8_t __attribute__((ext_vector_type(8)));
typedef float f32x4_t __attribute__((ext_vector_type(4)));

#define D_MODEL 1024
#define SEQ 2048
#define BATCH 4
#define NROWS (BATCH * SEQ)
#define HDIM 128

constexpr int EPI_SILU_BIAS = 0;
constexpr int EPI_F32 = 1;
constexpr int EPI_BF16 = 2;
constexpr int EPI_ADD_F32 = 3;

__device__ __forceinline__ float bf2f(u16 u) {
  union { unsigned int i; float f; } v; v.i = ((unsigned int)u) << 16; return v.f;
}
__device__ __forceinline__ u16 f2bf(float f) {
  union { float f; unsigned int i; } v; v.f = f;
  unsigned int r = (v.i + 0x7FFFu + ((v.i >> 16) & 1u)) >> 16;
  return (u16)r;
}
__device__ __forceinline__ float silu_f(float x) { return x / (1.0f + __expf(-x)); }

// async global->LDS, 16B per lane. LDS dest must be wave-uniform base (HW adds lane*16).
__device__ __forceinline__ void load_lds16(const void* g, void* l) {
  auto gp = (const __attribute__((address_space(1))) char*)(uintptr_t)g;
  auto lp = (__attribute__((address_space(3))) char*)(uint32_t)(uintptr_t)l;
  __builtin_amdgcn_global_load_lds(gp, lp, 16, 0, 0);
}

__device__ __forceinline__ void block_sum2(float& a, float& b, float* sm) {
  #pragma unroll
  for (int off = 32; off > 0; off >>= 1) {
    a += __shfl_xor(a, off, 64);
    b += __shfl_xor(b, off, 64);
  }
  const int w = threadIdx.x >> 6;
  if ((threadIdx.x & 63) == 0) { sm[w] = a; sm[4 + w] = b; }
  __syncthreads();
  a = sm[0] + sm[1] + sm[2] + sm[3];
  b = sm[4] + sm[5] + sm[6] + sm[7];
}

// ---------------- weight fp32 [K][N] -> bf16 [N][K] (transposed) ----------------
__global__ __launch_bounds__(256)
void k_wconv(const float* __restrict__ W, u16* __restrict__ Wt, int K, int N) {
  __shared__ float tile[32][33];
  const int n0 = blockIdx.x * 32, k0 = blockIdx.y * 32;
  const int tx = threadIdx.x & 31, ty = threadIdx.x >> 5;
  #pragma unroll
  for (int i = 0; i < 4; i++)
    tile[ty + 8 * i][tx] = W[(size_t)(k0 + ty + 8 * i) * N + n0 + tx];
  __syncthreads();
  #pragma unroll
  for (int i = 0; i < 4; i++)
    Wt[(size_t)(n0 + ty + 8 * i) * K + k0 + tx] = f2bf(tile[tx][ty + 8 * i]);
}

// ---------------- input layernorm: fp32 [row][1024] -> bf16 ----------------
__global__ __launch_bounds__(256)
void k_ln_in(const float* __restrict__ X, const float* __restrict__ w,
             const float* __restrict__ b, u16* __restrict__ Y) {
  __shared__ float sm[8];
  const int row = blockIdx.x, t = threadIdx.x;
  const float4 v = ((const float4*)(X + (size_t)row * D_MODEL))[t];
  float s = v.x + v.y + v.z + v.w;
  float ss = v.x * v.x + v.y * v.y + v.z * v.z + v.w * v.w;
  block_sum2(s, ss, sm);
  const float mu = s * (1.0f / D_MODEL);
  const float var = ss * (1.0f / D_MODEL) - mu * mu;
  const float rs = rsqrtf(var + 1e-5f);
  const float4 wv = ((const float4*)w)[t];
  const float4 bv = ((const float4*)b)[t];
  ushort4 o;
  o.x = f2bf((v.x - mu) * rs * wv.x + bv.x);
  o.y = f2bf((v.y - mu) * rs * wv.y + bv.y);
  o.z = f2bf((v.z - mu) * rs * wv.z + bv.z);
  o.w = f2bf((v.w - mu) * rs * wv.w + bv.w);
  ((ushort4*)(Y + (size_t)row * D_MODEL))[t] = o;
}

// ---------------- parallel = user * layernorm(attn) ----------------
__global__ __launch_bounds__(256)
void k_gated(const u16* __restrict__ attn, const u16* __restrict__ mixed,
             const float* __restrict__ w, const float* __restrict__ b,
             u16* __restrict__ out) {
  __shared__ float sm[8];
  const int row = blockIdx.x, t = threadIdx.x;
  const ushort4 av = ((const ushort4*)(attn + (size_t)row * D_MODEL))[t];
  const float x0 = bf2f(av.x), x1 = bf2f(av.y), x2 = bf2f(av.z), x3 = bf2f(av.w);
  float s = x0 + x1 + x2 + x3;
  float ss = x0 * x0 + x1 * x1 + x2 * x2 + x3 * x3;
  block_sum2(s, ss, sm);
  const float mu = s * (1.0f / D_MODEL);
  const float rs = rsqrtf(ss * (1.0f / D_MODEL) - mu * mu + 1e-5f);
  const ushort4 uv = ((const ushort4*)(mixed + (size_t)row * 4096))[t]; // user = cols 0..1023
  const float4 wv = ((const float4*)w)[t];
  const float4 bv = ((const float4*)b)[t];
  ushort4 o;
  o.x = f2bf(bf2f(uv.x) * ((x0 - mu) * rs * wv.x + bv.x));
  o.y = f2bf(bf2f(uv.y) * ((x1 - mu) * rs * wv.y + bv.y));
  o.z = f2bf(bf2f(uv.z) * ((x2 - mu) * rs * wv.z + bv.z));
  o.w = f2bf(bf2f(uv.w) * ((x3 - mu) * rs * wv.w + bv.w));
  ((ushort4*)(out + (size_t)row * D_MODEL))[t] = o;
}

// ---------------- ffn_in = rmsnorm(layer_output + layer_input) ----------------
__global__ __launch_bounds__(256)
void k_rms(const float* __restrict__ lo, const float* __restrict__ li,
           const float* __restrict__ w, u16* __restrict__ out) {
  __shared__ float sm[8];
  const int row = blockIdx.x, t = threadIdx.x;
  const float4 a = ((const float4*)(lo + (size_t)row * D_MODEL))[t];
  const float4 bq = ((const float4*)(li + (size_t)row * D_MODEL))[t];
  const float x0 = a.x + bq.x, x1 = a.y + bq.y, x2 = a.z + bq.z, x3 = a.w + bq.w;
  float ss = x0 * x0 + x1 * x1 + x2 * x2 + x3 * x3, dummy = 0.f;
  block_sum2(ss, dummy, sm);
  const float rs = rsqrtf(ss * (1.0f / D_MODEL) + 1e-5f);
  const float4 wv = ((const float4*)w)[t];
  ushort4 o;
  o.x = f2bf(x0 * rs * wv.x);
  o.y = f2bf(x1 * rs * wv.y);
  o.z = f2bf(x2 * rs * wv.z);
  o.w = f2bf(x3 * rs * wv.w);
  ((ushort4*)(out + (size_t)row * D_MODEL))[t] = o;
}

// ---------------- g = silu(h[:, :1024]) * h[:, 1024:2048] ----------------
__global__ __launch_bounds__(256)
void k_silumul(const u16* __restrict__ h, u16* __restrict__ g) {
  const int row = blockIdx.x, t = threadIdx.x;
  const ushort4 a = ((const ushort4*)(h + (size_t)row * 2048))[t];
  const ushort4 b = ((const ushort4*)(h + (size_t)row * 2048 + 1024))[t];
  ushort4 o;
  o.x = f2bf(silu_f(bf2f(a.x)) * bf2f(b.x));
  o.y = f2bf(silu_f(bf2f(a.y)) * bf2f(b.y));
  o.z = f2bf(silu_f(bf2f(a.z)) * bf2f(b.z));
  o.w = f2bf(silu_f(bf2f(a.w)) * bf2f(b.w));
  ((ushort4*)(g + (size_t)row * D_MODEL))[t] = o;
}

// ---------------- GEMM: C[M,N] = A[M,K] @ Bt[N,K]^T, bf16 in, fp32 acc ----------------
// XCD-clustered block remap (T1): flat id f -> v = (f&7)*per + f>>3 (bijective,
// total % 8 == 0). Each XCD gets contiguous v-range = NB/8 whole n-bands:
// its B-panel (<=1MB) stays L2-resident; A-panels get n-band reuse within XCD.
template <int EPI>
__global__ __launch_bounds__(256, 2)
void k_gemm(const u16* __restrict__ A, const u16* __restrict__ Bt,
            void* __restrict__ Cout, const float* __restrict__ bias,
            const float* __restrict__ addsrc, int M, int N, int K) {
  __shared__ u16 As[128 * 64];
  __shared__ u16 Bs[128 * 64];
  const int t = threadIdx.x, lane = t & 63, w = t >> 6;
  const int l15 = lane & 15, l4 = lane >> 4;
  const int wr = w >> 1, wc = w & 1;
  const int flat = blockIdx.y * gridDim.x + blockIdx.x;
  const int per = (gridDim.x * gridDim.y) >> 3;
  const int v = (flat & 7) * per + (flat >> 3);
  const int m0 = (v & 63) * 128, n0 = (v >> 6) * 128;
  const int lr = lane >> 3, lc = lane & 7;
  const int swz = (lc ^ lr) * 8; // pre-swizzled global k-offset (elements)

  f32x4_t acc[4][4];
  #pragma unroll
  for (int mi = 0; mi < 4; mi++)
    #pragma unroll
    for (int ni = 0; ni < 4; ni++) {
      acc[mi][ni][0] = 0.f; acc[mi][ni][1] = 0.f; acc[mi][ni][2] = 0.f; acc[mi][ni][3] = 0.f;
    }

  const u16* Ab = A + (size_t)m0 * K + swz;
  const u16* Bb = Bt + (size_t)n0 * K + swz;

  for (int kt = 0; kt < K; kt += 64) {
    #pragma unroll
    for (int j = 0; j < 4; j++) {
      const size_t rr = (size_t)((w * 4 + j) * 8 + lr);
      load_lds16(Ab + rr * K + kt, &As[(w * 4 + j) * 512]);
      load_lds16(Bb + rr * K + kt, &Bs[(w * 4 + j) * 512]);
    }
    __syncthreads();
    #pragma unroll
    for (int kk = 0; kk < 2; kk++) {
      bf16x8_t af[4], bf[4];
      #pragma unroll
      for (int mi = 0; mi < 4; mi++) {
        const int row = wr * 64 + mi * 16 + l15;
        const int cph = (kk * 4 + l4) ^ (row & 7);
        af[mi] = *(const bf16x8_t*)&As[row * 64 + cph * 8];
      }
      #pragma unroll
      for (int ni = 0; ni < 4; ni++) {
        const int row = wc * 64 + ni * 16 + l15;
        const int cph = (kk * 4 + l4) ^ (row & 7);
        bf[ni] = *(const bf16x8_t*)&Bs[row * 64 + cph * 8];
      }
      #pragma unroll
      for (int mi = 0; mi < 4; mi++)
        #pragma unroll
        for (int ni = 0; ni < 4; ni++)
          acc[mi][ni] = __builtin_amdgcn_mfma_f32_16x16x32_bf16(af[mi], bf[ni], acc[mi][ni], 0, 0, 0);
    }
    __syncthreads();
  }

  #pragma unroll
  for (int mi = 0; mi < 4; mi++) {
    #pragma unroll
    for (int ni = 0; ni < 4; ni++) {
      const int col = n0 + wc * 64 + ni * 16 + l15;
      float bv = 0.f;
      if constexpr (EPI == EPI_SILU_BIAS) bv = bias[col];
      #pragma unroll
      for (int r = 0; r < 4; r++) {
        const size_t row = (size_t)(m0 + wr * 64 + mi * 16 + l4 * 4 + r);
        float v2 = acc[mi][ni][r];
        if constexpr (EPI == EPI_SILU_BIAS) {
          v2 += bv;
          ((u16*)Cout)[row * N + col] = f2bf(silu_f(v2));
        } else if constexpr (EPI == EPI_BF16) {
          ((u16*)Cout)[row * N + col] = f2bf(v2);
        } else if constexpr (EPI == EPI_F32) {
          ((float*)Cout)[row * N + col] = v2;
        } else {
          ((float*)Cout)[row * N + col] = v2 + addsrc[row * N + col];
        }
      }
    }
  }
}

// ---------------- repack K and V^T into dense per-head tiles ----------------
// Kc[bh][2048][128]: row-contiguous (64-key tile = dense 16KB).
// Vtc[bh][kt][128][64]: transposed tile-major (PV operand tile = dense 16KB).
__global__ __launch_bounds__(256)
void k_qkvprep(const u16* __restrict__ mixed, u16* __restrict__ Kc, u16* __restrict__ Vtc) {
  __shared__ u16 Vl[64 * 132];
  const int kt = blockIdx.x, bh = blockIdx.y, bI = bh >> 3, h = bh & 7;
  const int kb = kt * 64, t = threadIdx.x;
  const u16* base = mixed + (size_t)bI * SEQ * 4096;
  const int kcol = 3 * D_MODEL + h * HDIM;
  const int vcol = 1 * D_MODEL + h * HDIM;
  #pragma unroll
  for (int j = 0; j < 4; j++) {
    const int n = j * 256 + t, kr = n >> 4, c8 = n & 15;
    const uint4 kv = *(const uint4*)(base + (size_t)(kb + kr) * 4096 + kcol + c8 * 8);
    *(uint4*)(Kc + ((size_t)bh * SEQ + kb + kr) * 128 + c8 * 8) = kv;
    const uint4 vv = *(const uint4*)(base + (size_t)(kb + kr) * 4096 + vcol + c8 * 8);
    *(uint4*)&Vl[kr * 132 + c8 * 8] = vv;
  }
  __syncthreads();
  u16* vt = Vtc + ((size_t)bh * 32 + kt) * 8192;
  #pragma unroll
  for (int j = 0; j < 4; j++) {
    const int n = j * 256 + t, d = n >> 3, g8 = n & 7;
    u16 tmp[8];
    #pragma unroll
    for (int i = 0; i < 8; i++) tmp[i] = Vl[(g8 * 8 + i) * 132 + d];
    *(uint4*)(vt + d * 64 + g8 * 8) = *(const uint4*)tmp;
  }
}

// ---------------- split-K flash attention (R15 body, XCD-clustered bh) ----------
// grid: flat 768 blocks. XCD remap: v=(f%8)*96+f/8 (bijective) so each XCD's
// 96 blocks cover 4 heads -> Kc/Vtc working set 4MB = one XCD L2.
// Then v -> ci = v%24, bh = v/24; ci<16: qt=15-(ci>>1), ch=ci&1 (split qts 8..15);
// ci>=16: qt=23-ci single-chunk.
__global__ __launch_bounds__(256, 2)
void k_attn(const u16* __restrict__ mixed, const u16* __restrict__ Kc,
            const u16* __restrict__ Vtc, u16* __restrict__ attnb,
            u16* __restrict__ o_part, float* __restrict__ ml) {
  __shared__ u16 Ks[64 * 128];   // [key][d], 16B-granule swizzled by key&7
  __shared__ u16 Vts[128 * 64];  // [d][key], swizzled by (d&7)^((d>>3)&7)
  __shared__ u16 Ps[4 * 16 * 64];// per-wave P half-tiles (8KB)
  const int t = threadIdx.x, lane = t & 63, w = t >> 6;
  const int l15 = lane & 15, l4 = lane >> 4;
  const int f = blockIdx.x;
  const int v = (f & 7) * 96 + (f >> 3);   // XCD-clustering bijection (768 = 8*96)
  const int ci = v % 24, bh = v / 24;
  const int bI = bh >> 3, h = bh & 7;
  int qt, ch;
  if (ci < 16) { qt = 15 - (ci >> 1); ch = ci & 1; }
  else { qt = 23 - ci; ch = 0; }
  const bool split = (qt >= 8);
  const int qb = qt * 128;
  const int nt_all = 2 * qt + 2;
  const int t0 = (split && ch == 1) ? (qt + 1) : 0;
  const int t1 = (split && ch == 0) ? (qt + 1) : nt_all;

  const u16* base = mixed + (size_t)bI * SEQ * 4096;
  const int qcol = 2 * D_MODEL + h * HDIM;
  const int qrow0 = qb + w * 32;
  const u16* Kh = Kc + (size_t)bh * SEQ * 128;
  const u16* Vh = Vtc + (size_t)bh * 32 * 8192;

  const int nk = lane;

  bf16x8_t qf[2][4];
  #pragma unroll
  for (int mi = 0; mi < 2; mi++) {
    const u16* qp = base + (size_t)(qrow0 + mi * 16 + l15) * 4096 + qcol + l4 * 8;
    #pragma unroll
    for (int ks = 0; ks < 4; ks++) qf[mi][ks] = *(const bf16x8_t*)(qp + ks * 32);
  }

  f32x4_t o[2][8];
  #pragma unroll
  for (int mi = 0; mi < 2; mi++)
    #pragma unroll
    for (int df = 0; df < 8; df++) { o[mi][df][0] = 0.f; o[mi][df][1] = 0.f; o[mi][df][2] = 0.f; o[mi][df][3] = 0.f; }
  float mrun[2][4], lrun[2][4];
  #pragma unroll
  for (int mi = 0; mi < 2; mi++)
    #pragma unroll
    for (int r = 0; r < 4; r++) { mrun[mi][r] = -1e30f; lrun[mi][r] = 0.f; }

  const float alpha = 0.08838834764831845f; // 1/sqrt(128)

  // ---- stage(tile): 8 global_load_lds per thread into single buffers ----
  auto stage = [&](int tile) {
    const u16* Kt = Kh + (size_t)(tile * 64) * 128;
    const u16* Vt = Vh + (size_t)tile * 8192;
    #pragma unroll
    for (int j = 0; j < 4; j++) {
      const int slot = j * 4 + w;
      const int kr = slot * 4 + (nk >> 4), gk = nk & 15;
      load_lds16(Kt + kr * 128 + ((gk ^ (kr & 7)) * 8), &Ks[slot * 512]);
      const int d = slot * 8 + (nk >> 3), gv = nk & 7;
      load_lds16(Vt + d * 64 + ((gv ^ (d & 7) ^ ((d >> 3) & 7)) * 8), &Vts[slot * 512]);
    }
  };

  for (int it = t0; it < t1; it++) {
    const int kb = it * 64;
    stage(it);
    __syncthreads(); // drain stage — covered by other resident blocks

    const bool active = (kb <= qrow0 + 31);
    const bool needmask = (kb + 63 > qrow0);
    if (active) {
      f32x4_t s[2][4];
      #pragma unroll
      for (int mi = 0; mi < 2; mi++)
        #pragma unroll
        for (int ni = 0; ni < 4; ni++) { s[mi][ni][0] = 0.f; s[mi][ni][1] = 0.f; s[mi][ni][2] = 0.f; s[mi][ni][3] = 0.f; }
      #pragma unroll
      for (int ks = 0; ks < 4; ks++) {
        bf16x8_t kf[4];
        #pragma unroll
        for (int ni = 0; ni < 4; ni++) {
          const int key = ni * 16 + l15;
          const int cph = (ks * 4 + l4) ^ (key & 7);
          kf[ni] = *(const bf16x8_t*)&Ks[key * 128 + cph * 8];
        }
        #pragma unroll
        for (int mi = 0; mi < 2; mi++)
          #pragma unroll
          for (int ni = 0; ni < 4; ni++)
            s[mi][ni] = __builtin_amdgcn_mfma_f32_16x16x32_bf16(qf[mi][ks], kf[ni], s[mi][ni], 0, 0, 0);
      }
      #pragma unroll
      for (int mi = 0; mi < 2; mi++) {
        #pragma unroll
        for (int r = 0; r < 4; r++) {
          const int qr = qrow0 + mi * 16 + l4 * 4 + r;
          float mx = -1e30f;
          #pragma unroll
          for (int ni = 0; ni < 4; ni++) {
            float v2 = s[mi][ni][r] * alpha;
            if (needmask) {
              const int key = kb + ni * 16 + l15;
              if (key > qr) v2 = -1e30f;
            }
            s[mi][ni][r] = v2;
            mx = fmaxf(mx, v2);
          }
          #pragma unroll
          for (int off = 1; off < 16; off <<= 1) mx = fmaxf(mx, __shfl_xor(mx, off, 64));
          const float mnew = fmaxf(mrun[mi][r], mx);
          const float fsc = __expf(mrun[mi][r] - mnew);
          mrun[mi][r] = mnew;
          lrun[mi][r] *= fsc;
          #pragma unroll
          for (int df = 0; df < 8; df++) o[mi][df][r] *= fsc;
          float ls = 0.f;
          #pragma unroll
          for (int ni = 0; ni < 4; ni++) {
            const float p = __expf(s[mi][ni][r] - mnew);
            s[mi][ni][r] = p;
            ls += p;
          }
          #pragma unroll
          for (int off = 1; off < 16; off <<= 1) ls += __shfl_xor(ls, off, 64);
          lrun[mi][r] += ls;
        }
        // P half-tile write (per-wave private region; wave-local ordering)
        #pragma unroll
        for (int ni = 0; ni < 4; ni++)
          #pragma unroll
          for (int r = 0; r < 4; r++) {
            const int pr = l4 * 4 + r;
            const int pc = ni * 16 + l15;
            Ps[w * 1024 + pr * 64 + (((pc >> 3) ^ (pr & 7)) * 8) + (pc & 7)] = f2bf(s[mi][ni][r]);
          }
        // PV for this half
        #pragma unroll
        for (int ks2 = 0; ks2 < 2; ks2++) {
          bf16x8_t pa;
          {
            const int pr = l15;
            const int cph = (ks2 * 4 + l4) ^ (pr & 7);
            pa = *(const bf16x8_t*)&Ps[w * 1024 + pr * 64 + cph * 8];
          }
          #pragma unroll
          for (int df = 0; df < 8; df++) {
            const int d = df * 16 + l15;
            const int cph = (ks2 * 4 + l4) ^ (d & 7) ^ ((d >> 3) & 7);
            const bf16x8_t vb = *(const bf16x8_t*)&Vts[d * 64 + cph * 8];
            o[mi][df] = __builtin_amdgcn_mfma_f32_16x16x32_bf16(pa, vb, o[mi][df], 0, 0, 0);
          }
        }
      }
    }
    __syncthreads(); // reads of Ks/Vts done before next tile's stage
  }

  if (!split) {
    #pragma unroll
    for (int mi = 0; mi < 2; mi++) {
      #pragma unroll
      for (int r = 0; r < 4; r++) {
        const float inv = 1.0f / lrun[mi][r];
        const size_t row = (size_t)bI * SEQ + qrow0 + mi * 16 + l4 * 4 + r;
        #pragma unroll
        for (int df = 0; df < 8; df++)
          attnb[row * D_MODEL + h * HDIM + df * 16 + l15] = f2bf(o[mi][df][r] * inv);
      }
    }
  } else {
    const int sl = bh * 8 + (qt - 8);
    #pragma unroll
    for (int mi = 0; mi < 2; mi++) {
      #pragma unroll
      for (int r = 0; r < 4; r++) {
        const int pr = w * 32 + mi * 16 + l4 * 4 + r;
        if (l15 == 0) {
          ml[sl * 512 + ch * 256 + pr] = mrun[mi][r];
          ml[sl * 512 + ch * 256 + 128 + pr] = lrun[mi][r];
        }
        if (ch == 0) {
          const size_t row = (size_t)bI * SEQ + qb + pr;
          #pragma unroll
          for (int df = 0; df < 8; df++)
            attnb[row * D_MODEL + h * HDIM + df * 16 + l15] = f2bf(o[mi][df][r]);
        } else {
          #pragma unroll
          for (int df = 0; df < 8; df++)
            o_part[(size_t)sl * 16384 + pr * 128 + df * 16 + l15] = f2bf(o[mi][df][r]);
        }
      }
    }
  }
}

// ---------------- combine split chunks for qt 8..15 ----------------
// grid: (8, 32). 256 threads: 2 per row, 64 d each.
__global__ __launch_bounds__(256)
void k_combine(const u16* __restrict__ o_part, const float* __restrict__ ml,
               u16* __restrict__ attnb) {
  const int qti = blockIdx.x, bh = blockIdx.y;
  const int bI = bh >> 3, h = bh & 7;
  const int t = threadIdx.x;
  const int pr = t >> 1, half = t & 1;
  const int sl = bh * 8 + qti;
  const float m0 = ml[sl * 512 + pr];
  const float l0 = ml[sl * 512 + 128 + pr];
  const float m1 = ml[sl * 512 + 256 + pr];
  const float l1 = ml[sl * 512 + 384 + pr];
  const float M = fmaxf(m0, m1);
  const float w0 = __expf(m0 - M), w1 = __expf(m1 - M);
  const float inv = 1.0f / (w0 * l0 + w1 * l1);
  const float c0 = w0 * inv, c1 = w1 * inv;
  const size_t row = (size_t)bI * SEQ + (8 + qti) * 128 + pr;
  u16* ap = attnb + row * D_MODEL + h * HDIM + half * 64;
  const u16* pp = o_part + (size_t)sl * 16384 + pr * 128 + half * 64;
  #pragma unroll
  for (int j = 0; j < 8; j++) {
    u16 a[8], b[8], c[8];
    *(uint4*)a = ((const uint4*)ap)[j];
    *(uint4*)b = ((const uint4*)pp)[j];
    #pragma unroll
    for (int i = 0; i < 8; i++) c[i] = f2bf(c0 * bf2f(a[i]) + c1 * bf2f(b[i]));
    ((uint4*)ap)[j] = *(const uint4*)c;
  }
}

extern "C" void kernel_launch(void* const* d_in, const int* in_sizes, int n_in,
                              void* d_out, int out_size, void* d_ws, size_t ws_size,
                              hipStream_t stream) {
  (void)in_sizes; (void)n_in; (void)out_size; (void)ws_size;
  const float* layer_input = (const float*)d_in[0];
  // d_in[1] = positions (unused by reference)
  const float* ln_in_w  = (const float*)d_in[2];
  const float* ln_in_b  = (const float*)d_in[3];
  const float* W_uvqk   = (const float*)d_in[4];
  const float* b_uvqk   = (const float*)d_in[5];
  const float* ln_out_w = (const float*)d_in[6];
  const float* ln_out_b = (const float*)d_in[7];
  const float* W_proj   = (const float*)d_in[8];
  const float* rms_w    = (const float*)d_in[9];
  const float* W1       = (const float*)d_in[10];
  const float* W2       = (const float*)d_in[11];
  float* out = (float*)d_out;

  char* ws = (char*)d_ws;
  u16* buf0    = (u16*)(ws);                          // 16 MB: normed/gated/ffn_in/g
  u16* mixed   = (u16*)(ws + ((size_t)16 << 20));     // 64 MB: uvqk out; later h
  u16* attnb   = (u16*)(ws + ((size_t)80 << 20));     // 16 MB
  float* lout  = (float*)(ws + ((size_t)96 << 20));   // 32 MB: layer_output fp32 (post-attn)
  u16* Kc      = (u16*)(ws + ((size_t)96 << 20));     // 16 MB dense K (dead before proj)
  u16* Vtc     = (u16*)(ws + ((size_t)112 << 20));    // 16 MB dense V^T tiles (dead before proj)
  u16* wt_uvqk = (u16*)(ws + ((size_t)128 << 20));    // 8 MB
  u16* wt_proj = (u16*)(ws + ((size_t)136 << 20));    // 2 MB
  u16* wt_1    = (u16*)(ws + ((size_t)138 << 20));    // 4 MB
  u16* wt_2    = (u16*)(ws + ((size_t)142 << 20));    // 2 MB
  // split-K scratch lives in d_out (fully overwritten by the final GEMM):
  u16* o_part  = (u16*)d_out;                          // 8 MB partials (256 slots x 32KB)
  float* ml    = (float*)((char*)d_out + ((size_t)20 << 20)); // 512 KB m/l

  k_wconv<<<dim3(128, 32), 256, 0, stream>>>(W_uvqk, wt_uvqk, 1024, 4096);
  k_wconv<<<dim3(32, 32), 256, 0, stream>>>(W_proj, wt_proj, 1024, 1024);
  k_wconv<<<dim3(64, 32), 256, 0, stream>>>(W1, wt_1, 1024, 2048);
  k_wconv<<<dim3(32, 32), 256, 0, stream>>>(W2, wt_2, 1024, 1024);

  k_ln_in<<<NROWS, 256, 0, stream>>>(layer_input, ln_in_w, ln_in_b, buf0);
  k_gemm<EPI_SILU_BIAS><<<dim3(64, 32), 256, 0, stream>>>(buf0, wt_uvqk, mixed, b_uvqk, nullptr, NROWS, 4096, 1024);
  k_qkvprep<<<dim3(32, 32), 256, 0, stream>>>(mixed, Kc, Vtc);
  k_attn<<<768, 256, 0, stream>>>(mixed, Kc, Vtc, attnb, o_part, ml);
  k_combine<<<dim3(8, 32), 256, 0, stream>>>(o_part, ml, attnb);
  k_gated<<<NROWS, 256, 0, stream>>>(attnb, mixed, ln_out_w, ln_out_b, buf0);
  k_gemm<EPI_F32><<<dim3(64, 8), 256, 0, stream>>>(buf0, wt_proj, lout, nullptr, nullptr, NROWS, 1024, 1024);
  k_rms<<<NROWS, 256, 0, stream>>>(lout, layer_input, rms_w, buf0);
  k_gemm<EPI_BF16><<<dim3(64, 16), 256, 0, stream>>>(buf0, wt_1, mixed, nullptr, nullptr, NROWS, 2048, 1024);
  k_silumul<<<NROWS, 256, 0, stream>>>(mixed, buf0);
  k_gemm<EPI_ADD_F32><<<dim3(64, 8), 256, 0, stream>>>(buf0, wt_2, out, nullptr, lout, NROWS, 1024, 1024);
}

// Round 21
// 378.825 us; speedup vs baseline: 1.0635x; 1.0635x over previous
//
#include <hip/hip_runtime.h>
#include <stdint.h>

typedef unsigned short u16;
typedef __bf16 bf16x8_t __attribute__((ext_vector_type(8)));
typedef float f32x4_t __attribute__((ext_vector_type(4)));

#define D_MODEL 1024
#define SEQ 2048
#define BATCH 4
#define NROWS (BATCH * SEQ)
#define HDIM 128

constexpr int EPI_SILU_BIAS = 0;
constexpr int EPI_F32 = 1;
constexpr int EPI_BF16 = 2;
constexpr int EPI_ADD_F32 = 3;

__device__ __forceinline__ float bf2f(u16 u) {
  union { unsigned int i; float f; } v; v.i = ((unsigned int)u) << 16; return v.f;
}
__device__ __forceinline__ u16 f2bf(float f) {
  union { float f; unsigned int i; } v; v.f = f;
  unsigned int r = (v.i + 0x7FFFu + ((v.i >> 16) & 1u)) >> 16;
  return (u16)r;
}
__device__ __forceinline__ float silu_f(float x) { return x / (1.0f + __expf(-x)); }

// async global->LDS, 16B per lane. LDS dest must be wave-uniform base (HW adds lane*16).
__device__ __forceinline__ void load_lds16(const void* g, void* l) {
  auto gp = (const __attribute__((address_space(1))) char*)(uintptr_t)g;
  auto lp = (__attribute__((address_space(3))) char*)(uint32_t)(uintptr_t)l;
  __builtin_amdgcn_global_load_lds(gp, lp, 16, 0, 0);
}

__device__ __forceinline__ void block_sum2(float& a, float& b, float* sm) {
  #pragma unroll
  for (int off = 32; off > 0; off >>= 1) {
    a += __shfl_xor(a, off, 64);
    b += __shfl_xor(b, off, 64);
  }
  const int w = threadIdx.x >> 6;
  if ((threadIdx.x & 63) == 0) { sm[w] = a; sm[4 + w] = b; }
  __syncthreads();
  a = sm[0] + sm[1] + sm[2] + sm[3];
  b = sm[4] + sm[5] + sm[6] + sm[7];
}

// ---------------- weight fp32 [K][N] -> bf16 [N][K] (transposed) ----------------
__global__ __launch_bounds__(256)
void k_wconv(const float* __restrict__ W, u16* __restrict__ Wt, int K, int N) {
  __shared__ float tile[32][33];
  const int n0 = blockIdx.x * 32, k0 = blockIdx.y * 32;
  const int tx = threadIdx.x & 31, ty = threadIdx.x >> 5;
  #pragma unroll
  for (int i = 0; i < 4; i++)
    tile[ty + 8 * i][tx] = W[(size_t)(k0 + ty + 8 * i) * N + n0 + tx];
  __syncthreads();
  #pragma unroll
  for (int i = 0; i < 4; i++)
    Wt[(size_t)(n0 + ty + 8 * i) * K + k0 + tx] = f2bf(tile[tx][ty + 8 * i]);
}

// ---------------- input layernorm: fp32 [row][1024] -> bf16 ----------------
__global__ __launch_bounds__(256)
void k_ln_in(const float* __restrict__ X, const float* __restrict__ w,
             const float* __restrict__ b, u16* __restrict__ Y) {
  __shared__ float sm[8];
  const int row = blockIdx.x, t = threadIdx.x;
  const float4 v = ((const float4*)(X + (size_t)row * D_MODEL))[t];
  float s = v.x + v.y + v.z + v.w;
  float ss = v.x * v.x + v.y * v.y + v.z * v.z + v.w * v.w;
  block_sum2(s, ss, sm);
  const float mu = s * (1.0f / D_MODEL);
  const float var = ss * (1.0f / D_MODEL) - mu * mu;
  const float rs = rsqrtf(var + 1e-5f);
  const float4 wv = ((const float4*)w)[t];
  const float4 bv = ((const float4*)b)[t];
  ushort4 o;
  o.x = f2bf((v.x - mu) * rs * wv.x + bv.x);
  o.y = f2bf((v.y - mu) * rs * wv.y + bv.y);
  o.z = f2bf((v.z - mu) * rs * wv.z + bv.z);
  o.w = f2bf((v.w - mu) * rs * wv.w + bv.w);
  ((ushort4*)(Y + (size_t)row * D_MODEL))[t] = o;
}

// ---------------- parallel = user * layernorm(attn) ----------------
__global__ __launch_bounds__(256)
void k_gated(const u16* __restrict__ attn, const u16* __restrict__ mixed,
             const float* __restrict__ w, const float* __restrict__ b,
             u16* __restrict__ out) {
  __shared__ float sm[8];
  const int row = blockIdx.x, t = threadIdx.x;
  const ushort4 av = ((const ushort4*)(attn + (size_t)row * D_MODEL))[t];
  const float x0 = bf2f(av.x), x1 = bf2f(av.y), x2 = bf2f(av.z), x3 = bf2f(av.w);
  float s = x0 + x1 + x2 + x3;
  float ss = x0 * x0 + x1 * x1 + x2 * x2 + x3 * x3;
  block_sum2(s, ss, sm);
  const float mu = s * (1.0f / D_MODEL);
  const float rs = rsqrtf(ss * (1.0f / D_MODEL) - mu * mu + 1e-5f);
  const ushort4 uv = ((const ushort4*)(mixed + (size_t)row * 4096))[t]; // user = cols 0..1023
  const float4 wv = ((const float4*)w)[t];
  const float4 bv = ((const float4*)b)[t];
  ushort4 o;
  o.x = f2bf(bf2f(uv.x) * ((x0 - mu) * rs * wv.x + bv.x));
  o.y = f2bf(bf2f(uv.y) * ((x1 - mu) * rs * wv.y + bv.y));
  o.z = f2bf(bf2f(uv.z) * ((x2 - mu) * rs * wv.z + bv.z));
  o.w = f2bf(bf2f(uv.w) * ((x3 - mu) * rs * wv.w + bv.w));
  ((ushort4*)(out + (size_t)row * D_MODEL))[t] = o;
}

// ---------------- ffn_in = rmsnorm(layer_output + layer_input) ----------------
__global__ __launch_bounds__(256)
void k_rms(const float* __restrict__ lo, const float* __restrict__ li,
           const float* __restrict__ w, u16* __restrict__ out) {
  __shared__ float sm[8];
  const int row = blockIdx.x, t = threadIdx.x;
  const float4 a = ((const float4*)(lo + (size_t)row * D_MODEL))[t];
  const float4 bq = ((const float4*)(li + (size_t)row * D_MODEL))[t];
  const float x0 = a.x + bq.x, x1 = a.y + bq.y, x2 = a.z + bq.z, x3 = a.w + bq.w;
  float ss = x0 * x0 + x1 * x1 + x2 * x2 + x3 * x3, dummy = 0.f;
  block_sum2(ss, dummy, sm);
  const float rs = rsqrtf(ss * (1.0f / D_MODEL) + 1e-5f);
  const float4 wv = ((const float4*)w)[t];
  ushort4 o;
  o.x = f2bf(x0 * rs * wv.x);
  o.y = f2bf(x1 * rs * wv.y);
  o.z = f2bf(x2 * rs * wv.z);
  o.w = f2bf(x3 * rs * wv.w);
  ((ushort4*)(out + (size_t)row * D_MODEL))[t] = o;
}

// ---------------- g = silu(h[:, :1024]) * h[:, 1024:2048] ----------------
__global__ __launch_bounds__(256)
void k_silumul(const u16* __restrict__ h, u16* __restrict__ g) {
  const int row = blockIdx.x, t = threadIdx.x;
  const ushort4 a = ((const ushort4*)(h + (size_t)row * 2048))[t];
  const ushort4 b = ((const ushort4*)(h + (size_t)row * 2048 + 1024))[t];
  ushort4 o;
  o.x = f2bf(silu_f(bf2f(a.x)) * bf2f(b.x));
  o.y = f2bf(silu_f(bf2f(a.y)) * bf2f(b.y));
  o.z = f2bf(silu_f(bf2f(a.z)) * bf2f(b.z));
  o.w = f2bf(silu_f(bf2f(a.w)) * bf2f(b.w));
  ((ushort4*)(g + (size_t)row * D_MODEL))[t] = o;
}

// ---------------- GEMM: C[M,N] = A[M,K] @ Bt[N,K]^T, bf16 in, fp32 acc ----------------
// Baseline block mapping (R19): consecutive blocks share an n-band, so all 8
// XCDs co-stream the same A panel (cross-XCD broadcast) and each XCD's B slice
// is 256KB (L2-resident). R20 measured: XCD-clustered remap HURTS here (-24us).
template <int EPI>
__global__ __launch_bounds__(256, 2)
void k_gemm(const u16* __restrict__ A, const u16* __restrict__ Bt,
            void* __restrict__ Cout, const float* __restrict__ bias,
            const float* __restrict__ addsrc, int M, int N, int K) {
  __shared__ u16 As[128 * 64];
  __shared__ u16 Bs[128 * 64];
  const int t = threadIdx.x, lane = t & 63, w = t >> 6;
  const int l15 = lane & 15, l4 = lane >> 4;
  const int wr = w >> 1, wc = w & 1;
  const int m0 = blockIdx.x * 128, n0 = blockIdx.y * 128;
  const int lr = lane >> 3, lc = lane & 7;
  const int swz = (lc ^ lr) * 8; // pre-swizzled global k-offset (elements)

  f32x4_t acc[4][4];
  #pragma unroll
  for (int mi = 0; mi < 4; mi++)
    #pragma unroll
    for (int ni = 0; ni < 4; ni++) {
      acc[mi][ni][0] = 0.f; acc[mi][ni][1] = 0.f; acc[mi][ni][2] = 0.f; acc[mi][ni][3] = 0.f;
    }

  const u16* Ab = A + (size_t)m0 * K + swz;
  const u16* Bb = Bt + (size_t)n0 * K + swz;

  for (int kt = 0; kt < K; kt += 64) {
    #pragma unroll
    for (int j = 0; j < 4; j++) {
      const size_t rr = (size_t)((w * 4 + j) * 8 + lr);
      load_lds16(Ab + rr * K + kt, &As[(w * 4 + j) * 512]);
      load_lds16(Bb + rr * K + kt, &Bs[(w * 4 + j) * 512]);
    }
    __syncthreads();
    #pragma unroll
    for (int kk = 0; kk < 2; kk++) {
      bf16x8_t af[4], bf[4];
      #pragma unroll
      for (int mi = 0; mi < 4; mi++) {
        const int row = wr * 64 + mi * 16 + l15;
        const int cph = (kk * 4 + l4) ^ (row & 7);
        af[mi] = *(const bf16x8_t*)&As[row * 64 + cph * 8];
      }
      #pragma unroll
      for (int ni = 0; ni < 4; ni++) {
        const int row = wc * 64 + ni * 16 + l15;
        const int cph = (kk * 4 + l4) ^ (row & 7);
        bf[ni] = *(const bf16x8_t*)&Bs[row * 64 + cph * 8];
      }
      #pragma unroll
      for (int mi = 0; mi < 4; mi++)
        #pragma unroll
        for (int ni = 0; ni < 4; ni++)
          acc[mi][ni] = __builtin_amdgcn_mfma_f32_16x16x32_bf16(af[mi], bf[ni], acc[mi][ni], 0, 0, 0);
    }
    __syncthreads();
  }

  #pragma unroll
  for (int mi = 0; mi < 4; mi++) {
    #pragma unroll
    for (int ni = 0; ni < 4; ni++) {
      const int col = n0 + wc * 64 + ni * 16 + l15;
      float bv = 0.f;
      if constexpr (EPI == EPI_SILU_BIAS) bv = bias[col];
      #pragma unroll
      for (int r = 0; r < 4; r++) {
        const size_t row = (size_t)(m0 + wr * 64 + mi * 16 + l4 * 4 + r);
        float v = acc[mi][ni][r];
        if constexpr (EPI == EPI_SILU_BIAS) {
          v += bv;
          ((u16*)Cout)[row * N + col] = f2bf(silu_f(v));
        } else if constexpr (EPI == EPI_BF16) {
          ((u16*)Cout)[row * N + col] = f2bf(v);
        } else if constexpr (EPI == EPI_F32) {
          ((float*)Cout)[row * N + col] = v;
        } else {
          ((float*)Cout)[row * N + col] = v + addsrc[row * N + col];
        }
      }
    }
  }
}

// ---------------- repack K and V^T into dense per-head tiles ----------------
// Kc[bh][2048][128]: row-contiguous (64-key tile = dense 16KB).
// Vtc[bh][kt][128][64]: transposed tile-major (PV operand tile = dense 16KB).
__global__ __launch_bounds__(256)
void k_qkvprep(const u16* __restrict__ mixed, u16* __restrict__ Kc, u16* __restrict__ Vtc) {
  __shared__ u16 Vl[64 * 132];
  const int kt = blockIdx.x, bh = blockIdx.y, bI = bh >> 3, h = bh & 7;
  const int kb = kt * 64, t = threadIdx.x;
  const u16* base = mixed + (size_t)bI * SEQ * 4096;
  const int kcol = 3 * D_MODEL + h * HDIM;
  const int vcol = 1 * D_MODEL + h * HDIM;
  #pragma unroll
  for (int j = 0; j < 4; j++) {
    const int n = j * 256 + t, kr = n >> 4, c8 = n & 15;
    const uint4 kv = *(const uint4*)(base + (size_t)(kb + kr) * 4096 + kcol + c8 * 8);
    *(uint4*)(Kc + ((size_t)bh * SEQ + kb + kr) * 128 + c8 * 8) = kv;
    const uint4 vv = *(const uint4*)(base + (size_t)(kb + kr) * 4096 + vcol + c8 * 8);
    *(uint4*)&Vl[kr * 132 + c8 * 8] = vv;
  }
  __syncthreads();
  u16* vt = Vtc + ((size_t)bh * 32 + kt) * 8192;
  #pragma unroll
  for (int j = 0; j < 4; j++) {
    const int n = j * 256 + t, d = n >> 3, g8 = n & 7;
    u16 tmp[8];
    #pragma unroll
    for (int i = 0; i < 8; i++) tmp[i] = Vl[(g8 * 8 + i) * 132 + d];
    *(uint4*)(vt + d * 64 + g8 * 8) = *(const uint4*)tmp;
  }
}

// ---------------- split-K flash attention (R15 body, XCD-clustered bh) ----------
// grid: flat 768 blocks. XCD remap: v=(f%8)*96+f/8 (bijective) so each XCD's
// 96 blocks cover 4 heads -> Kc/Vtc working set 4MB = one XCD L2.
// Then v -> ci = v%24, bh = v/24; ci<16: qt=15-(ci>>1), ch=ci&1 (split qts 8..15);
// ci>=16: qt=23-ci single-chunk.
__global__ __launch_bounds__(256, 2)
void k_attn(const u16* __restrict__ mixed, const u16* __restrict__ Kc,
            const u16* __restrict__ Vtc, u16* __restrict__ attnb,
            u16* __restrict__ o_part, float* __restrict__ ml) {
  __shared__ u16 Ks[64 * 128];   // [key][d], 16B-granule swizzled by key&7
  __shared__ u16 Vts[128 * 64];  // [d][key], swizzled by (d&7)^((d>>3)&7)
  __shared__ u16 Ps[4 * 16 * 64];// per-wave P half-tiles (8KB)
  const int t = threadIdx.x, lane = t & 63, w = t >> 6;
  const int l15 = lane & 15, l4 = lane >> 4;
  const int f = blockIdx.x;
  const int v = (f & 7) * 96 + (f >> 3);   // XCD-clustering bijection (768 = 8*96)
  const int ci = v % 24, bh = v / 24;
  const int bI = bh >> 3, h = bh & 7;
  int qt, ch;
  if (ci < 16) { qt = 15 - (ci >> 1); ch = ci & 1; }
  else { qt = 23 - ci; ch = 0; }
  const bool split = (qt >= 8);
  const int qb = qt * 128;
  const int nt_all = 2 * qt + 2;
  const int t0 = (split && ch == 1) ? (qt + 1) : 0;
  const int t1 = (split && ch == 0) ? (qt + 1) : nt_all;

  const u16* base = mixed + (size_t)bI * SEQ * 4096;
  const int qcol = 2 * D_MODEL + h * HDIM;
  const int qrow0 = qb + w * 32;
  const u16* Kh = Kc + (size_t)bh * SEQ * 128;
  const u16* Vh = Vtc + (size_t)bh * 32 * 8192;

  const int nk = lane;

  bf16x8_t qf[2][4];
  #pragma unroll
  for (int mi = 0; mi < 2; mi++) {
    const u16* qp = base + (size_t)(qrow0 + mi * 16 + l15) * 4096 + qcol + l4 * 8;
    #pragma unroll
    for (int ks = 0; ks < 4; ks++) qf[mi][ks] = *(const bf16x8_t*)(qp + ks * 32);
  }

  f32x4_t o[2][8];
  #pragma unroll
  for (int mi = 0; mi < 2; mi++)
    #pragma unroll
    for (int df = 0; df < 8; df++) { o[mi][df][0] = 0.f; o[mi][df][1] = 0.f; o[mi][df][2] = 0.f; o[mi][df][3] = 0.f; }
  float mrun[2][4], lrun[2][4];
  #pragma unroll
  for (int mi = 0; mi < 2; mi++)
    #pragma unroll
    for (int r = 0; r < 4; r++) { mrun[mi][r] = -1e30f; lrun[mi][r] = 0.f; }

  const float alpha = 0.08838834764831845f; // 1/sqrt(128)

  // ---- stage(tile): 8 global_load_lds per thread into single buffers ----
  auto stage = [&](int tile) {
    const u16* Kt = Kh + (size_t)(tile * 64) * 128;
    const u16* Vt = Vh + (size_t)tile * 8192;
    #pragma unroll
    for (int j = 0; j < 4; j++) {
      const int slot = j * 4 + w;
      const int kr = slot * 4 + (nk >> 4), gk = nk & 15;
      load_lds16(Kt + kr * 128 + ((gk ^ (kr & 7)) * 8), &Ks[slot * 512]);
      const int d = slot * 8 + (nk >> 3), gv = nk & 7;
      load_lds16(Vt + d * 64 + ((gv ^ (d & 7) ^ ((d >> 3) & 7)) * 8), &Vts[slot * 512]);
    }
  };

  for (int it = t0; it < t1; it++) {
    const int kb = it * 64;
    stage(it);
    __syncthreads(); // drain stage — covered by other resident blocks

    const bool active = (kb <= qrow0 + 31);
    const bool needmask = (kb + 63 > qrow0);
    if (active) {
      f32x4_t s[2][4];
      #pragma unroll
      for (int mi = 0; mi < 2; mi++)
        #pragma unroll
        for (int ni = 0; ni < 4; ni++) { s[mi][ni][0] = 0.f; s[mi][ni][1] = 0.f; s[mi][ni][2] = 0.f; s[mi][ni][3] = 0.f; }
      #pragma unroll
      for (int ks = 0; ks < 4; ks++) {
        bf16x8_t kf[4];
        #pragma unroll
        for (int ni = 0; ni < 4; ni++) {
          const int key = ni * 16 + l15;
          const int cph = (ks * 4 + l4) ^ (key & 7);
          kf[ni] = *(const bf16x8_t*)&Ks[key * 128 + cph * 8];
        }
        #pragma unroll
        for (int mi = 0; mi < 2; mi++)
          #pragma unroll
          for (int ni = 0; ni < 4; ni++)
            s[mi][ni] = __builtin_amdgcn_mfma_f32_16x16x32_bf16(qf[mi][ks], kf[ni], s[mi][ni], 0, 0, 0);
      }
      #pragma unroll
      for (int mi = 0; mi < 2; mi++) {
        #pragma unroll
        for (int r = 0; r < 4; r++) {
          const int qr = qrow0 + mi * 16 + l4 * 4 + r;
          float mx = -1e30f;
          #pragma unroll
          for (int ni = 0; ni < 4; ni++) {
            float v2 = s[mi][ni][r] * alpha;
            if (needmask) {
              const int key = kb + ni * 16 + l15;
              if (key > qr) v2 = -1e30f;
            }
            s[mi][ni][r] = v2;
            mx = fmaxf(mx, v2);
          }
          #pragma unroll
          for (int off = 1; off < 16; off <<= 1) mx = fmaxf(mx, __shfl_xor(mx, off, 64));
          const float mnew = fmaxf(mrun[mi][r], mx);
          const float fsc = __expf(mrun[mi][r] - mnew);
          mrun[mi][r] = mnew;
          lrun[mi][r] *= fsc;
          #pragma unroll
          for (int df = 0; df < 8; df++) o[mi][df][r] *= fsc;
          float ls = 0.f;
          #pragma unroll
          for (int ni = 0; ni < 4; ni++) {
            const float p = __expf(s[mi][ni][r] - mnew);
            s[mi][ni][r] = p;
            ls += p;
          }
          #pragma unroll
          for (int off = 1; off < 16; off <<= 1) ls += __shfl_xor(ls, off, 64);
          lrun[mi][r] += ls;
        }
        // P half-tile write (per-wave private region; wave-local ordering)
        #pragma unroll
        for (int ni = 0; ni < 4; ni++)
          #pragma unroll
          for (int r = 0; r < 4; r++) {
            const int pr = l4 * 4 + r;
            const int pc = ni * 16 + l15;
            Ps[w * 1024 + pr * 64 + (((pc >> 3) ^ (pr & 7)) * 8) + (pc & 7)] = f2bf(s[mi][ni][r]);
          }
        // PV for this half
        #pragma unroll
        for (int ks2 = 0; ks2 < 2; ks2++) {
          bf16x8_t pa;
          {
            const int pr = l15;
            const int cph = (ks2 * 4 + l4) ^ (pr & 7);
            pa = *(const bf16x8_t*)&Ps[w * 1024 + pr * 64 + cph * 8];
          }
          #pragma unroll
          for (int df = 0; df < 8; df++) {
            const int d = df * 16 + l15;
            const int cph = (ks2 * 4 + l4) ^ (d & 7) ^ ((d >> 3) & 7);
            const bf16x8_t vb = *(const bf16x8_t*)&Vts[d * 64 + cph * 8];
            o[mi][df] = __builtin_amdgcn_mfma_f32_16x16x32_bf16(pa, vb, o[mi][df], 0, 0, 0);
          }
        }
      }
    }
    __syncthreads(); // reads of Ks/Vts done before next tile's stage
  }

  if (!split) {
    #pragma unroll
    for (int mi = 0; mi < 2; mi++) {
      #pragma unroll
      for (int r = 0; r < 4; r++) {
        const float inv = 1.0f / lrun[mi][r];
        const size_t row = (size_t)bI * SEQ + qrow0 + mi * 16 + l4 * 4 + r;
        #pragma unroll
        for (int df = 0; df < 8; df++)
          attnb[row * D_MODEL + h * HDIM + df * 16 + l15] = f2bf(o[mi][df][r] * inv);
      }
    }
  } else {
    const int sl = bh * 8 + (qt - 8);
    #pragma unroll
    for (int mi = 0; mi < 2; mi++) {
      #pragma unroll
      for (int r = 0; r < 4; r++) {
        const int pr = w * 32 + mi * 16 + l4 * 4 + r;
        if (l15 == 0) {
          ml[sl * 512 + ch * 256 + pr] = mrun[mi][r];
          ml[sl * 512 + ch * 256 + 128 + pr] = lrun[mi][r];
        }
        if (ch == 0) {
          const size_t row = (size_t)bI * SEQ + qb + pr;
          #pragma unroll
          for (int df = 0; df < 8; df++)
            attnb[row * D_MODEL + h * HDIM + df * 16 + l15] = f2bf(o[mi][df][r]);
        } else {
          #pragma unroll
          for (int df = 0; df < 8; df++)
            o_part[(size_t)sl * 16384 + pr * 128 + df * 16 + l15] = f2bf(o[mi][df][r]);
        }
      }
    }
  }
}

// ---------------- combine split chunks for qt 8..15 ----------------
// grid: (8, 32). 256 threads: 2 per row, 64 d each.
__global__ __launch_bounds__(256)
void k_combine(const u16* __restrict__ o_part, const float* __restrict__ ml,
               u16* __restrict__ attnb) {
  const int qti = blockIdx.x, bh = blockIdx.y;
  const int bI = bh >> 3, h = bh & 7;
  const int t = threadIdx.x;
  const int pr = t >> 1, half = t & 1;
  const int sl = bh * 8 + qti;
  const float m0 = ml[sl * 512 + pr];
  const float l0 = ml[sl * 512 + 128 + pr];
  const float m1 = ml[sl * 512 + 256 + pr];
  const float l1 = ml[sl * 512 + 384 + pr];
  const float M = fmaxf(m0, m1);
  const float w0 = __expf(m0 - M), w1 = __expf(m1 - M);
  const float inv = 1.0f / (w0 * l0 + w1 * l1);
  const float c0 = w0 * inv, c1 = w1 * inv;
  const size_t row = (size_t)bI * SEQ + (8 + qti) * 128 + pr;
  u16* ap = attnb + row * D_MODEL + h * HDIM + half * 64;
  const u16* pp = o_part + (size_t)sl * 16384 + pr * 128 + half * 64;
  #pragma unroll
  for (int j = 0; j < 8; j++) {
    u16 a[8], b[8], c[8];
    *(uint4*)a = ((const uint4*)ap)[j];
    *(uint4*)b = ((const uint4*)pp)[j];
    #pragma unroll
    for (int i = 0; i < 8; i++) c[i] = f2bf(c0 * bf2f(a[i]) + c1 * bf2f(b[i]));
    ((uint4*)ap)[j] = *(const uint4*)c;
  }
}

extern "C" void kernel_launch(void* const* d_in, const int* in_sizes, int n_in,
                              void* d_out, int out_size, void* d_ws, size_t ws_size,
                              hipStream_t stream) {
  (void)in_sizes; (void)n_in; (void)out_size; (void)ws_size;
  const float* layer_input = (const float*)d_in[0];
  // d_in[1] = positions (unused by reference)
  const float* ln_in_w  = (const float*)d_in[2];
  const float* ln_in_b  = (const float*)d_in[3];
  const float* W_uvqk   = (const float*)d_in[4];
  const float* b_uvqk   = (const float*)d_in[5];
  const float* ln_out_w = (const float*)d_in[6];
  const float* ln_out_b = (const float*)d_in[7];
  const float* W_proj   = (const float*)d_in[8];
  const float* rms_w    = (const float*)d_in[9];
  const float* W1       = (const float*)d_in[10];
  const float* W2       = (const float*)d_in[11];
  float* out = (float*)d_out;

  char* ws = (char*)d_ws;
  u16* buf0    = (u16*)(ws);                          // 16 MB: normed/gated/ffn_in/g
  u16* mixed   = (u16*)(ws + ((size_t)16 << 20));     // 64 MB: uvqk out; later h
  u16* attnb   = (u16*)(ws + ((size_t)80 << 20));     // 16 MB
  float* lout  = (float*)(ws + ((size_t)96 << 20));   // 32 MB: layer_output fp32 (post-attn)
  u16* Kc      = (u16*)(ws + ((size_t)96 << 20));     // 16 MB dense K (dead before proj)
  u16* Vtc     = (u16*)(ws + ((size_t)112 << 20));    // 16 MB dense V^T tiles (dead before proj)
  u16* wt_uvqk = (u16*)(ws + ((size_t)128 << 20));    // 8 MB
  u16* wt_proj = (u16*)(ws + ((size_t)136 << 20));    // 2 MB
  u16* wt_1    = (u16*)(ws + ((size_t)138 << 20));    // 4 MB
  u16* wt_2    = (u16*)(ws + ((size_t)142 << 20));    // 2 MB
  // split-K scratch lives in d_out (fully overwritten by the final GEMM):
  u16* o_part  = (u16*)d_out;                          // 8 MB partials (256 slots x 32KB)
  float* ml    = (float*)((char*)d_out + ((size_t)20 << 20)); // 512 KB m/l

  k_wconv<<<dim3(128, 32), 256, 0, stream>>>(W_uvqk, wt_uvqk, 1024, 4096);
  k_wconv<<<dim3(32, 32), 256, 0, stream>>>(W_proj, wt_proj, 1024, 1024);
  k_wconv<<<dim3(64, 32), 256, 0, stream>>>(W1, wt_1, 1024, 2048);
  k_wconv<<<dim3(32, 32), 256, 0, stream>>>(W2, wt_2, 1024, 1024);

  k_ln_in<<<NROWS, 256, 0, stream>>>(layer_input, ln_in_w, ln_in_b, buf0);
  k_gemm<EPI_SILU_BIAS><<<dim3(64, 32), 256, 0, stream>>>(buf0, wt_uvqk, mixed, b_uvqk, nullptr, NROWS, 4096, 1024);
  k_qkvprep<<<dim3(32, 32), 256, 0, stream>>>(mixed, Kc, Vtc);
  k_attn<<<768, 256, 0, stream>>>(mixed, Kc, Vtc, attnb, o_part, ml);
  k_combine<<<dim3(8, 32), 256, 0, stream>>>(o_part, ml, attnb);
  k_gated<<<NROWS, 256, 0, stream>>>(attnb, mixed, ln_out_w, ln_out_b, buf0);
  k_gemm<EPI_F32><<<dim3(64, 8), 256, 0, stream>>>(buf0, wt_proj, lout, nullptr, nullptr, NROWS, 1024, 1024);
  k_rms<<<NROWS, 256, 0, stream>>>(lout, layer_input, rms_w, buf0);
  k_gemm<EPI_BF16><<<dim3(64, 16), 256, 0, stream>>>(buf0, wt_1, mixed, nullptr, nullptr, NROWS, 2048, 1024);
  k_silumul<<<NROWS, 256, 0, stream>>>(mixed, buf0);
  k_gemm<EPI_ADD_F32><<<dim3(64, 8), 256, 0, stream>>>(buf0, wt_2, out, nullptr, lout, NROWS, 1024, 1024);
}

// Round 22
// 370.420 us; speedup vs baseline: 1.0876x; 1.0227x over previous
//
#include <hip/hip_runtime.h>
#include <stdint.h>

typedef unsigned short u16;
typedef __bf16 bf16x8_t __attribute__((ext_vector_type(8)));
typedef float f32x4_t __attribute__((ext_vector_type(4)));

#define D_MODEL 1024
#define SEQ 2048
#define BATCH 4
#define NROWS (BATCH * SEQ)
#define HDIM 128

constexpr int EPI_UVQK = 0;    // silu+bias; route user/Q->mixed, V->Vtc, K->Kc
constexpr int EPI_F32 = 1;
constexpr int EPI_BF16 = 2;
constexpr int EPI_ADD_F32 = 3;

__device__ __forceinline__ float bf2f(u16 u) {
  union { unsigned int i; float f; } v; v.i = ((unsigned int)u) << 16; return v.f;
}
__device__ __forceinline__ u16 f2bf(float f) {
  union { float f; unsigned int i; } v; v.f = f;
  unsigned int r = (v.i + 0x7FFFu + ((v.i >> 16) & 1u)) >> 16;
  return (u16)r;
}
__device__ __forceinline__ float silu_f(float x) { return x / (1.0f + __expf(-x)); }

// async global->LDS, 16B per lane. LDS dest must be wave-uniform base (HW adds lane*16).
__device__ __forceinline__ void load_lds16(const void* g, void* l) {
  auto gp = (const __attribute__((address_space(1))) char*)(uintptr_t)g;
  auto lp = (__attribute__((address_space(3))) char*)(uint32_t)(uintptr_t)l;
  __builtin_amdgcn_global_load_lds(gp, lp, 16, 0, 0);
}

__device__ __forceinline__ void block_sum2(float& a, float& b, float* sm) {
  #pragma unroll
  for (int off = 32; off > 0; off >>= 1) {
    a += __shfl_xor(a, off, 64);
    b += __shfl_xor(b, off, 64);
  }
  const int w = threadIdx.x >> 6;
  if ((threadIdx.x & 63) == 0) { sm[w] = a; sm[4 + w] = b; }
  __syncthreads();
  a = sm[0] + sm[1] + sm[2] + sm[3];
  b = sm[4] + sm[5] + sm[6] + sm[7];
}

// ---------------- weight fp32 [K][N] -> bf16 [N][K] (transposed) ----------------
__global__ __launch_bounds__(256)
void k_wconv(const float* __restrict__ W, u16* __restrict__ Wt, int K, int N) {
  __shared__ float tile[32][33];
  const int n0 = blockIdx.x * 32, k0 = blockIdx.y * 32;
  const int tx = threadIdx.x & 31, ty = threadIdx.x >> 5;
  #pragma unroll
  for (int i = 0; i < 4; i++)
    tile[ty + 8 * i][tx] = W[(size_t)(k0 + ty + 8 * i) * N + n0 + tx];
  __syncthreads();
  #pragma unroll
  for (int i = 0; i < 4; i++)
    Wt[(size_t)(n0 + ty + 8 * i) * K + k0 + tx] = f2bf(tile[tx][ty + 8 * i]);
}

// ---------------- input layernorm: fp32 [row][1024] -> bf16 ----------------
__global__ __launch_bounds__(256)
void k_ln_in(const float* __restrict__ X, const float* __restrict__ w,
             const float* __restrict__ b, u16* __restrict__ Y) {
  __shared__ float sm[8];
  const int row = blockIdx.x, t = threadIdx.x;
  const float4 v = ((const float4*)(X + (size_t)row * D_MODEL))[t];
  float s = v.x + v.y + v.z + v.w;
  float ss = v.x * v.x + v.y * v.y + v.z * v.z + v.w * v.w;
  block_sum2(s, ss, sm);
  const float mu = s * (1.0f / D_MODEL);
  const float var = ss * (1.0f / D_MODEL) - mu * mu;
  const float rs = rsqrtf(var + 1e-5f);
  const float4 wv = ((const float4*)w)[t];
  const float4 bv = ((const float4*)b)[t];
  ushort4 o;
  o.x = f2bf((v.x - mu) * rs * wv.x + bv.x);
  o.y = f2bf((v.y - mu) * rs * wv.y + bv.y);
  o.z = f2bf((v.z - mu) * rs * wv.z + bv.z);
  o.w = f2bf((v.w - mu) * rs * wv.w + bv.w);
  ((ushort4*)(Y + (size_t)row * D_MODEL))[t] = o;
}

// ---------------- parallel = user * layernorm(attn) ----------------
__global__ __launch_bounds__(256)
void k_gated(const u16* __restrict__ attn, const u16* __restrict__ mixed,
             const float* __restrict__ w, const float* __restrict__ b,
             u16* __restrict__ out) {
  __shared__ float sm[8];
  const int row = blockIdx.x, t = threadIdx.x;
  const ushort4 av = ((const ushort4*)(attn + (size_t)row * D_MODEL))[t];
  const float x0 = bf2f(av.x), x1 = bf2f(av.y), x2 = bf2f(av.z), x3 = bf2f(av.w);
  float s = x0 + x1 + x2 + x3;
  float ss = x0 * x0 + x1 * x1 + x2 * x2 + x3 * x3;
  block_sum2(s, ss, sm);
  const float mu = s * (1.0f / D_MODEL);
  const float rs = rsqrtf(ss * (1.0f / D_MODEL) - mu * mu + 1e-5f);
  const ushort4 uv = ((const ushort4*)(mixed + (size_t)row * 4096))[t]; // user = cols 0..1023
  const float4 wv = ((const float4*)w)[t];
  const float4 bv = ((const float4*)b)[t];
  ushort4 o;
  o.x = f2bf(bf2f(uv.x) * ((x0 - mu) * rs * wv.x + bv.x));
  o.y = f2bf(bf2f(uv.y) * ((x1 - mu) * rs * wv.y + bv.y));
  o.z = f2bf(bf2f(uv.z) * ((x2 - mu) * rs * wv.z + bv.z));
  o.w = f2bf(bf2f(uv.w) * ((x3 - mu) * rs * wv.w + bv.w));
  ((ushort4*)(out + (size_t)row * D_MODEL))[t] = o;
}

// ---------------- ffn_in = rmsnorm(layer_output + layer_input) ----------------
__global__ __launch_bounds__(256)
void k_rms(const float* __restrict__ lo, const float* __restrict__ li,
           const float* __restrict__ w, u16* __restrict__ out) {
  __shared__ float sm[8];
  const int row = blockIdx.x, t = threadIdx.x;
  const float4 a = ((const float4*)(lo + (size_t)row * D_MODEL))[t];
  const float4 bq = ((const float4*)(li + (size_t)row * D_MODEL))[t];
  const float x0 = a.x + bq.x, x1 = a.y + bq.y, x2 = a.z + bq.z, x3 = a.w + bq.w;
  float ss = x0 * x0 + x1 * x1 + x2 * x2 + x3 * x3, dummy = 0.f;
  block_sum2(ss, dummy, sm);
  const float rs = rsqrtf(ss * (1.0f / D_MODEL) + 1e-5f);
  const float4 wv = ((const float4*)w)[t];
  ushort4 o;
  o.x = f2bf(x0 * rs * wv.x);
  o.y = f2bf(x1 * rs * wv.y);
  o.z = f2bf(x2 * rs * wv.z);
  o.w = f2bf(x3 * rs * wv.w);
  ((ushort4*)(out + (size_t)row * D_MODEL))[t] = o;
}

// ---------------- g = silu(h[:, :1024]) * h[:, 1024:2048] ----------------
__global__ __launch_bounds__(256)
void k_silumul(const u16* __restrict__ h, u16* __restrict__ g) {
  const int row = blockIdx.x, t = threadIdx.x;
  const ushort4 a = ((const ushort4*)(h + (size_t)row * 2048))[t];
  const ushort4 b = ((const ushort4*)(h + (size_t)row * 2048 + 1024))[t];
  ushort4 o;
  o.x = f2bf(silu_f(bf2f(a.x)) * bf2f(b.x));
  o.y = f2bf(silu_f(bf2f(a.y)) * bf2f(b.y));
  o.z = f2bf(silu_f(bf2f(a.z)) * bf2f(b.z));
  o.w = f2bf(silu_f(bf2f(a.w)) * bf2f(b.w));
  ((ushort4*)(g + (size_t)row * D_MODEL))[t] = o;
}

// ---------------- GEMM: C[M,N] = A[M,K] @ Bt[N,K]^T, bf16 in, fp32 acc ----------------
// Baseline block mapping (R19/R21-verified). EPI_UVQK fuses the qkvprep repack:
// user/Q quarters -> mixed (layout consumers unchanged); V quarter -> Vtc
// (ushort4 of 4 consecutive keys per lane); K quarter -> Kc (dense rows).
// K/V values identical to the old qkvprep path (same silu+bias, same rounding).
template <int EPI>
__global__ __launch_bounds__(256, 2)
void k_gemm(const u16* __restrict__ A, const u16* __restrict__ Bt,
            void* __restrict__ Cout, const float* __restrict__ bias,
            const float* __restrict__ addsrc,
            u16* __restrict__ kc, u16* __restrict__ vtc,
            int M, int N, int K) {
  __shared__ u16 As[128 * 64];
  __shared__ u16 Bs[128 * 64];
  const int t = threadIdx.x, lane = t & 63, w = t >> 6;
  const int l15 = lane & 15, l4 = lane >> 4;
  const int wr = w >> 1, wc = w & 1;
  const int m0 = blockIdx.x * 128, n0 = blockIdx.y * 128;
  const int lr = lane >> 3, lc = lane & 7;
  const int swz = (lc ^ lr) * 8; // pre-swizzled global k-offset (elements)

  f32x4_t acc[4][4];
  #pragma unroll
  for (int mi = 0; mi < 4; mi++)
    #pragma unroll
    for (int ni = 0; ni < 4; ni++) {
      acc[mi][ni][0] = 0.f; acc[mi][ni][1] = 0.f; acc[mi][ni][2] = 0.f; acc[mi][ni][3] = 0.f;
    }

  const u16* Ab = A + (size_t)m0 * K + swz;
  const u16* Bb = Bt + (size_t)n0 * K + swz;

  for (int kt = 0; kt < K; kt += 64) {
    #pragma unroll
    for (int j = 0; j < 4; j++) {
      const size_t rr = (size_t)((w * 4 + j) * 8 + lr);
      load_lds16(Ab + rr * K + kt, &As[(w * 4 + j) * 512]);
      load_lds16(Bb + rr * K + kt, &Bs[(w * 4 + j) * 512]);
    }
    __syncthreads();
    #pragma unroll
    for (int kk = 0; kk < 2; kk++) {
      bf16x8_t af[4], bf[4];
      #pragma unroll
      for (int mi = 0; mi < 4; mi++) {
        const int row = wr * 64 + mi * 16 + l15;
        const int cph = (kk * 4 + l4) ^ (row & 7);
        af[mi] = *(const bf16x8_t*)&As[row * 64 + cph * 8];
      }
      #pragma unroll
      for (int ni = 0; ni < 4; ni++) {
        const int row = wc * 64 + ni * 16 + l15;
        const int cph = (kk * 4 + l4) ^ (row & 7);
        bf[ni] = *(const bf16x8_t*)&Bs[row * 64 + cph * 8];
      }
      #pragma unroll
      for (int mi = 0; mi < 4; mi++)
        #pragma unroll
        for (int ni = 0; ni < 4; ni++)
          acc[mi][ni] = __builtin_amdgcn_mfma_f32_16x16x32_bf16(af[mi], bf[ni], acc[mi][ni], 0, 0, 0);
    }
    __syncthreads();
  }

  #pragma unroll
  for (int mi = 0; mi < 4; mi++) {
    #pragma unroll
    for (int ni = 0; ni < 4; ni++) {
      const int col = n0 + wc * 64 + ni * 16 + l15;
      float bv = 0.f;
      if constexpr (EPI == EPI_UVQK) bv = bias[col];
      if constexpr (EPI == EPI_UVQK) {
        const int rowb = m0 + wr * 64 + mi * 16 + l4 * 4; // 4-aligned base row
        u16 c4[4];
        #pragma unroll
        for (int r = 0; r < 4; r++) c4[r] = f2bf(silu_f(acc[mi][ni][r] + bv));
        if (col < 1024 || (col >= 2048 && col < 3072)) {
          // user / Q -> mixed (consumers read this layout)
          #pragma unroll
          for (int r = 0; r < 4; r++)
            ((u16*)Cout)[(size_t)(rowb + r) * N + col] = c4[r];
        } else if (col < 2048) {
          // V -> Vtc[bh][kt][d][key]; 4 consecutive keys -> one 8B store
          const int h = (col - 1024) >> 7, d = (col - 1024) & 127;
          const int bI = rowb >> 11, seqr = rowb & 2047;
          const size_t off = ((size_t)(bI * 8 + h) * 32 + (seqr >> 6)) * 8192 + d * 64 + (seqr & 63);
          *(ushort4*)&vtc[off] = *(const ushort4*)c4;
        } else {
          // K -> Kc[bh][seq][d]
          const int h = (col - 3072) >> 7, d = (col - 3072) & 127;
          const int bI = rowb >> 11, seqr = rowb & 2047;
          #pragma unroll
          for (int r = 0; r < 4; r++)
            kc[((size_t)(bI * 8 + h) * 2048 + seqr + r) * 128 + d] = c4[r];
        }
      } else {
        #pragma unroll
        for (int r = 0; r < 4; r++) {
          const size_t row = (size_t)(m0 + wr * 64 + mi * 16 + l4 * 4 + r);
          float v = acc[mi][ni][r];
          if constexpr (EPI == EPI_BF16) {
            ((u16*)Cout)[row * N + col] = f2bf(v);
          } else if constexpr (EPI == EPI_F32) {
            ((float*)Cout)[row * N + col] = v;
          } else {
            ((float*)Cout)[row * N + col] = v + addsrc[row * N + col];
          }
        }
      }
    }
  }
}

// ---------------- split-K flash attention (R15 body, XCD-clustered bh) ----------
// grid: flat 768 blocks. XCD remap: v=(f%8)*96+f/8 (bijective) so each XCD's
// 96 blocks cover 4 heads -> Kc/Vtc working set 4MB = one XCD L2.
// Then v -> ci = v%24, bh = v/24; ci<16: qt=15-(ci>>1), ch=ci&1 (split qts 8..15);
// ci>=16: qt=23-ci single-chunk.
__global__ __launch_bounds__(256, 2)
void k_attn(const u16* __restrict__ mixed, const u16* __restrict__ Kc,
            const u16* __restrict__ Vtc, u16* __restrict__ attnb,
            u16* __restrict__ o_part, float* __restrict__ ml) {
  __shared__ u16 Ks[64 * 128];   // [key][d], 16B-granule swizzled by key&7
  __shared__ u16 Vts[128 * 64];  // [d][key], swizzled by (d&7)^((d>>3)&7)
  __shared__ u16 Ps[4 * 16 * 64];// per-wave P half-tiles (8KB)
  const int t = threadIdx.x, lane = t & 63, w = t >> 6;
  const int l15 = lane & 15, l4 = lane >> 4;
  const int f = blockIdx.x;
  const int v = (f & 7) * 96 + (f >> 3);   // XCD-clustering bijection (768 = 8*96)
  const int ci = v % 24, bh = v / 24;
  const int bI = bh >> 3, h = bh & 7;
  int qt, ch;
  if (ci < 16) { qt = 15 - (ci >> 1); ch = ci & 1; }
  else { qt = 23 - ci; ch = 0; }
  const bool split = (qt >= 8);
  const int qb = qt * 128;
  const int nt_all = 2 * qt + 2;
  const int t0 = (split && ch == 1) ? (qt + 1) : 0;
  const int t1 = (split && ch == 0) ? (qt + 1) : nt_all;

  const u16* base = mixed + (size_t)bI * SEQ * 4096;
  const int qcol = 2 * D_MODEL + h * HDIM;
  const int qrow0 = qb + w * 32;
  const u16* Kh = Kc + (size_t)bh * SEQ * 128;
  const u16* Vh = Vtc + (size_t)bh * 32 * 8192;

  const int nk = lane;

  bf16x8_t qf[2][4];
  #pragma unroll
  for (int mi = 0; mi < 2; mi++) {
    const u16* qp = base + (size_t)(qrow0 + mi * 16 + l15) * 4096 + qcol + l4 * 8;
    #pragma unroll
    for (int ks = 0; ks < 4; ks++) qf[mi][ks] = *(const bf16x8_t*)(qp + ks * 32);
  }

  f32x4_t o[2][8];
  #pragma unroll
  for (int mi = 0; mi < 2; mi++)
    #pragma unroll
    for (int df = 0; df < 8; df++) { o[mi][df][0] = 0.f; o[mi][df][1] = 0.f; o[mi][df][2] = 0.f; o[mi][df][3] = 0.f; }
  float mrun[2][4], lrun[2][4];
  #pragma unroll
  for (int mi = 0; mi < 2; mi++)
    #pragma unroll
    for (int r = 0; r < 4; r++) { mrun[mi][r] = -1e30f; lrun[mi][r] = 0.f; }

  const float alpha = 0.08838834764831845f; // 1/sqrt(128)

  // ---- stage(tile): 8 global_load_lds per thread into single buffers ----
  auto stage = [&](int tile) {
    const u16* Kt = Kh + (size_t)(tile * 64) * 128;
    const u16* Vt = Vh + (size_t)tile * 8192;
    #pragma unroll
    for (int j = 0; j < 4; j++) {
      const int slot = j * 4 + w;
      const int kr = slot * 4 + (nk >> 4), gk = nk & 15;
      load_lds16(Kt + kr * 128 + ((gk ^ (kr & 7)) * 8), &Ks[slot * 512]);
      const int d = slot * 8 + (nk >> 3), gv = nk & 7;
      load_lds16(Vt + d * 64 + ((gv ^ (d & 7) ^ ((d >> 3) & 7)) * 8), &Vts[slot * 512]);
    }
  };

  for (int it = t0; it < t1; it++) {
    const int kb = it * 64;
    stage(it);
    __syncthreads(); // drain stage — covered by other resident blocks

    const bool active = (kb <= qrow0 + 31);
    const bool needmask = (kb + 63 > qrow0);
    if (active) {
      f32x4_t s[2][4];
      #pragma unroll
      for (int mi = 0; mi < 2; mi++)
        #pragma unroll
        for (int ni = 0; ni < 4; ni++) { s[mi][ni][0] = 0.f; s[mi][ni][1] = 0.f; s[mi][ni][2] = 0.f; s[mi][ni][3] = 0.f; }
      #pragma unroll
      for (int ks = 0; ks < 4; ks++) {
        bf16x8_t kf[4];
        #pragma unroll
        for (int ni = 0; ni < 4; ni++) {
          const int key = ni * 16 + l15;
          const int cph = (ks * 4 + l4) ^ (key & 7);
          kf[ni] = *(const bf16x8_t*)&Ks[key * 128 + cph * 8];
        }
        #pragma unroll
        for (int mi = 0; mi < 2; mi++)
          #pragma unroll
          for (int ni = 0; ni < 4; ni++)
            s[mi][ni] = __builtin_amdgcn_mfma_f32_16x16x32_bf16(qf[mi][ks], kf[ni], s[mi][ni], 0, 0, 0);
      }
      #pragma unroll
      for (int mi = 0; mi < 2; mi++) {
        #pragma unroll
        for (int r = 0; r < 4; r++) {
          const int qr = qrow0 + mi * 16 + l4 * 4 + r;
          float mx = -1e30f;
          #pragma unroll
          for (int ni = 0; ni < 4; ni++) {
            float v2 = s[mi][ni][r] * alpha;
            if (needmask) {
              const int key = kb + ni * 16 + l15;
              if (key > qr) v2 = -1e30f;
            }
            s[mi][ni][r] = v2;
            mx = fmaxf(mx, v2);
          }
          #pragma unroll
          for (int off = 1; off < 16; off <<= 1) mx = fmaxf(mx, __shfl_xor(mx, off, 64));
          const float mnew = fmaxf(mrun[mi][r], mx);
          const float fsc = __expf(mrun[mi][r] - mnew);
          mrun[mi][r] = mnew;
          lrun[mi][r] *= fsc;
          #pragma unroll
          for (int df = 0; df < 8; df++) o[mi][df][r] *= fsc;
          float ls = 0.f;
          #pragma unroll
          for (int ni = 0; ni < 4; ni++) {
            const float p = __expf(s[mi][ni][r] - mnew);
            s[mi][ni][r] = p;
            ls += p;
          }
          #pragma unroll
          for (int off = 1; off < 16; off <<= 1) ls += __shfl_xor(ls, off, 64);
          lrun[mi][r] += ls;
        }
        // P half-tile write (per-wave private region; wave-local ordering)
        #pragma unroll
        for (int ni = 0; ni < 4; ni++)
          #pragma unroll
          for (int r = 0; r < 4; r++) {
            const int pr = l4 * 4 + r;
            const int pc = ni * 16 + l15;
            Ps[w * 1024 + pr * 64 + (((pc >> 3) ^ (pr & 7)) * 8) + (pc & 7)] = f2bf(s[mi][ni][r]);
          }
        // PV for this half
        #pragma unroll
        for (int ks2 = 0; ks2 < 2; ks2++) {
          bf16x8_t pa;
          {
            const int pr = l15;
            const int cph = (ks2 * 4 + l4) ^ (pr & 7);
            pa = *(const bf16x8_t*)&Ps[w * 1024 + pr * 64 + cph * 8];
          }
          #pragma unroll
          for (int df = 0; df < 8; df++) {
            const int d = df * 16 + l15;
            const int cph = (ks2 * 4 + l4) ^ (d & 7) ^ ((d >> 3) & 7);
            const bf16x8_t vb = *(const bf16x8_t*)&Vts[d * 64 + cph * 8];
            o[mi][df] = __builtin_amdgcn_mfma_f32_16x16x32_bf16(pa, vb, o[mi][df], 0, 0, 0);
          }
        }
      }
    }
    __syncthreads(); // reads of Ks/Vts done before next tile's stage
  }

  if (!split) {
    #pragma unroll
    for (int mi = 0; mi < 2; mi++) {
      #pragma unroll
      for (int r = 0; r < 4; r++) {
        const float inv = 1.0f / lrun[mi][r];
        const size_t row = (size_t)bI * SEQ + qrow0 + mi * 16 + l4 * 4 + r;
        #pragma unroll
        for (int df = 0; df < 8; df++)
          attnb[row * D_MODEL + h * HDIM + df * 16 + l15] = f2bf(o[mi][df][r] * inv);
      }
    }
  } else {
    const int sl = bh * 8 + (qt - 8);
    #pragma unroll
    for (int mi = 0; mi < 2; mi++) {
      #pragma unroll
      for (int r = 0; r < 4; r++) {
        const int pr = w * 32 + mi * 16 + l4 * 4 + r;
        if (l15 == 0) {
          ml[sl * 512 + ch * 256 + pr] = mrun[mi][r];
          ml[sl * 512 + ch * 256 + 128 + pr] = lrun[mi][r];
        }
        if (ch == 0) {
          const size_t row = (size_t)bI * SEQ + qb + pr;
          #pragma unroll
          for (int df = 0; df < 8; df++)
            attnb[row * D_MODEL + h * HDIM + df * 16 + l15] = f2bf(o[mi][df][r]);
        } else {
          #pragma unroll
          for (int df = 0; df < 8; df++)
            o_part[(size_t)sl * 16384 + pr * 128 + df * 16 + l15] = f2bf(o[mi][df][r]);
        }
      }
    }
  }
}

// ---------------- combine split chunks for qt 8..15 ----------------
// grid: (8, 32). 256 threads: 2 per row, 64 d each.
__global__ __launch_bounds__(256)
void k_combine(const u16* __restrict__ o_part, const float* __restrict__ ml,
               u16* __restrict__ attnb) {
  const int qti = blockIdx.x, bh = blockIdx.y;
  const int bI = bh >> 3, h = bh & 7;
  const int t = threadIdx.x;
  const int pr = t >> 1, half = t & 1;
  const int sl = bh * 8 + qti;
  const float m0 = ml[sl * 512 + pr];
  const float l0 = ml[sl * 512 + 128 + pr];
  const float m1 = ml[sl * 512 + 256 + pr];
  const float l1 = ml[sl * 512 + 384 + pr];
  const float M = fmaxf(m0, m1);
  const float w0 = __expf(m0 - M), w1 = __expf(m1 - M);
  const float inv = 1.0f / (w0 * l0 + w1 * l1);
  const float c0 = w0 * inv, c1 = w1 * inv;
  const size_t row = (size_t)bI * SEQ + (8 + qti) * 128 + pr;
  u16* ap = attnb + row * D_MODEL + h * HDIM + half * 64;
  const u16* pp = o_part + (size_t)sl * 16384 + pr * 128 + half * 64;
  #pragma unroll
  for (int j = 0; j < 8; j++) {
    u16 a[8], b[8], c[8];
    *(uint4*)a = ((const uint4*)ap)[j];
    *(uint4*)b = ((const uint4*)pp)[j];
    #pragma unroll
    for (int i = 0; i < 8; i++) c[i] = f2bf(c0 * bf2f(a[i]) + c1 * bf2f(b[i]));
    ((uint4*)ap)[j] = *(const uint4*)c;
  }
}

extern "C" void kernel_launch(void* const* d_in, const int* in_sizes, int n_in,
                              void* d_out, int out_size, void* d_ws, size_t ws_size,
                              hipStream_t stream) {
  (void)in_sizes; (void)n_in; (void)out_size; (void)ws_size;
  const float* layer_input = (const float*)d_in[0];
  // d_in[1] = positions (unused by reference)
  const float* ln_in_w  = (const float*)d_in[2];
  const float* ln_in_b  = (const float*)d_in[3];
  const float* W_uvqk   = (const float*)d_in[4];
  const float* b_uvqk   = (const float*)d_in[5];
  const float* ln_out_w = (const float*)d_in[6];
  const float* ln_out_b = (const float*)d_in[7];
  const float* W_proj   = (const float*)d_in[8];
  const float* rms_w    = (const float*)d_in[9];
  const float* W1       = (const float*)d_in[10];
  const float* W2       = (const float*)d_in[11];
  float* out = (float*)d_out;

  char* ws = (char*)d_ws;
  u16* buf0    = (u16*)(ws);                          // 16 MB: normed/gated/ffn_in/g
  u16* mixed   = (u16*)(ws + ((size_t)16 << 20));     // 64 MB: uvqk out; later h
  u16* attnb   = (u16*)(ws + ((size_t)80 << 20));     // 16 MB
  float* lout  = (float*)(ws + ((size_t)96 << 20));   // 32 MB: layer_output fp32 (post-attn)
  u16* Kc      = (u16*)(ws + ((size_t)96 << 20));     // 16 MB dense K (dead before proj)
  u16* Vtc     = (u16*)(ws + ((size_t)112 << 20));    // 16 MB dense V^T tiles (dead before proj)
  u16* wt_uvqk = (u16*)(ws + ((size_t)128 << 20));    // 8 MB
  u16* wt_proj = (u16*)(ws + ((size_t)136 << 20));    // 2 MB
  u16* wt_1    = (u16*)(ws + ((size_t)138 << 20));    // 4 MB
  u16* wt_2    = (u16*)(ws + ((size_t)142 << 20));    // 2 MB
  // split-K scratch lives in d_out (fully overwritten by the final GEMM):
  u16* o_part  = (u16*)d_out;                          // 8 MB partials (256 slots x 32KB)
  float* ml    = (float*)((char*)d_out + ((size_t)20 << 20)); // 512 KB m/l

  k_wconv<<<dim3(128, 32), 256, 0, stream>>>(W_uvqk, wt_uvqk, 1024, 4096);
  k_wconv<<<dim3(32, 32), 256, 0, stream>>>(W_proj, wt_proj, 1024, 1024);
  k_wconv<<<dim3(64, 32), 256, 0, stream>>>(W1, wt_1, 1024, 2048);
  k_wconv<<<dim3(32, 32), 256, 0, stream>>>(W2, wt_2, 1024, 1024);

  k_ln_in<<<NROWS, 256, 0, stream>>>(layer_input, ln_in_w, ln_in_b, buf0);
  k_gemm<EPI_UVQK><<<dim3(64, 32), 256, 0, stream>>>(buf0, wt_uvqk, mixed, b_uvqk, nullptr, Kc, Vtc, NROWS, 4096, 1024);
  k_attn<<<768, 256, 0, stream>>>(mixed, Kc, Vtc, attnb, o_part, ml);
  k_combine<<<dim3(8, 32), 256, 0, stream>>>(o_part, ml, attnb);
  k_gated<<<NROWS, 256, 0, stream>>>(attnb, mixed, ln_out_w, ln_out_b, buf0);
  k_gemm<EPI_F32><<<dim3(64, 8), 256, 0, stream>>>(buf0, wt_proj, lout, nullptr, nullptr, nullptr, nullptr, NROWS, 1024, 1024);
  k_rms<<<NROWS, 256, 0, stream>>>(lout, layer_input, rms_w, buf0);
  k_gemm<EPI_BF16><<<dim3(64, 16), 256, 0, stream>>>(buf0, wt_1, mixed, nullptr, nullptr, nullptr, nullptr, NROWS, 2048, 1024);
  k_silumul<<<NROWS, 256, 0, stream>>>(mixed, buf0);
  k_gemm<EPI_ADD_F32><<<dim3(64, 8), 256, 0, stream>>>(buf0, wt_2, out, nullptr, lout, nullptr, nullptr, NROWS, 1024, 1024);
}

// Round 23
// 360.596 us; speedup vs baseline: 1.1172x; 1.0272x over previous
//
#include <hip/hip_runtime.h>
#include <stdint.h>

typedef unsigned short u16;
typedef __bf16 bf16x8_t __attribute__((ext_vector_type(8)));
typedef float f32x4_t __attribute__((ext_vector_type(4)));

#define D_MODEL 1024
#define SEQ 2048
#define BATCH 4
#define NROWS (BATCH * SEQ)
#define HDIM 128

constexpr int EPI_UVQK = 0;    // silu+bias; route user/Q->mixed, V->Vtc, K->Kc
constexpr int EPI_F32 = 1;
constexpr int EPI_SILUMUL = 2; // interleaved W1: g = silu(a)*b directly
constexpr int EPI_ADD_F32 = 3;

__device__ __forceinline__ float bf2f(u16 u) {
  union { unsigned int i; float f; } v; v.i = ((unsigned int)u) << 16; return v.f;
}
__device__ __forceinline__ u16 f2bf(float f) {
  union { float f; unsigned int i; } v; v.f = f;
  unsigned int r = (v.i + 0x7FFFu + ((v.i >> 16) & 1u)) >> 16;
  return (u16)r;
}
__device__ __forceinline__ float silu_f(float x) { return x / (1.0f + __expf(-x)); }

// async global->LDS, 16B per lane. LDS dest must be wave-uniform base (HW adds lane*16).
__device__ __forceinline__ void load_lds16(const void* g, void* l) {
  auto gp = (const __attribute__((address_space(1))) char*)(uintptr_t)g;
  auto lp = (__attribute__((address_space(3))) char*)(uint32_t)(uintptr_t)l;
  __builtin_amdgcn_global_load_lds(gp, lp, 16, 0, 0);
}

__device__ __forceinline__ void block_sum2(float& a, float& b, float* sm) {
  #pragma unroll
  for (int off = 32; off > 0; off >>= 1) {
    a += __shfl_xor(a, off, 64);
    b += __shfl_xor(b, off, 64);
  }
  const int w = threadIdx.x >> 6;
  if ((threadIdx.x & 63) == 0) { sm[w] = a; sm[4 + w] = b; }
  __syncthreads();
  a = sm[0] + sm[1] + sm[2] + sm[3];
  b = sm[4] + sm[5] + sm[6] + sm[7];
}

// ---------------- weight fp32 [K][N] -> bf16 [N][K] (transposed) ----------------
// ILV=1 (W1): 16-col-group interleave. Logical col n<1024 (a=w3) -> rows
// 32*(n/16)+(n%16); n>=1024 (b=w1) -> 32*((n-1024)/16)+16+((n-1024)%16).
// Pairs a-group j / b-group j land in adjacent 16-row groups of one 128-row
// GEMM block, so silu(a)*b pairs share a lane (ni even/odd) — no shuffles.
template <int ILV>
__global__ __launch_bounds__(256)
void k_wconv(const float* __restrict__ W, u16* __restrict__ Wt, int K, int N) {
  __shared__ float tile[32][33];
  const int n0 = blockIdx.x * 32, k0 = blockIdx.y * 32;
  const int tx = threadIdx.x & 31, ty = threadIdx.x >> 5;
  #pragma unroll
  for (int i = 0; i < 4; i++)
    tile[ty + 8 * i][tx] = W[(size_t)(k0 + ty + 8 * i) * N + n0 + tx];
  __syncthreads();
  #pragma unroll
  for (int i = 0; i < 4; i++) {
    const int nlog = n0 + ty + 8 * i;
    int rowp;
    if (ILV == 0) rowp = nlog;
    else rowp = (nlog < 1024) ? (32 * (nlog >> 4) + (nlog & 15))
                              : (32 * ((nlog - 1024) >> 4) + 16 + ((nlog - 1024) & 15));
    Wt[(size_t)rowp * K + k0 + tx] = f2bf(tile[tx][ty + 8 * i]);
  }
}

// ---------------- input layernorm: fp32 [row][1024] -> bf16 ----------------
__global__ __launch_bounds__(256)
void k_ln_in(const float* __restrict__ X, const float* __restrict__ w,
             const float* __restrict__ b, u16* __restrict__ Y) {
  __shared__ float sm[8];
  const int row = blockIdx.x, t = threadIdx.x;
  const float4 v = ((const float4*)(X + (size_t)row * D_MODEL))[t];
  float s = v.x + v.y + v.z + v.w;
  float ss = v.x * v.x + v.y * v.y + v.z * v.z + v.w * v.w;
  block_sum2(s, ss, sm);
  const float mu = s * (1.0f / D_MODEL);
  const float var = ss * (1.0f / D_MODEL) - mu * mu;
  const float rs = rsqrtf(var + 1e-5f);
  const float4 wv = ((const float4*)w)[t];
  const float4 bv = ((const float4*)b)[t];
  ushort4 o;
  o.x = f2bf((v.x - mu) * rs * wv.x + bv.x);
  o.y = f2bf((v.y - mu) * rs * wv.y + bv.y);
  o.z = f2bf((v.z - mu) * rs * wv.z + bv.z);
  o.w = f2bf((v.w - mu) * rs * wv.w + bv.w);
  ((ushort4*)(Y + (size_t)row * D_MODEL))[t] = o;
}

// ---------------- parallel = user * layernorm(attn) ----------------
__global__ __launch_bounds__(256)
void k_gated(const u16* __restrict__ attn, const u16* __restrict__ mixed,
             const float* __restrict__ w, const float* __restrict__ b,
             u16* __restrict__ out) {
  __shared__ float sm[8];
  const int row = blockIdx.x, t = threadIdx.x;
  const ushort4 av = ((const ushort4*)(attn + (size_t)row * D_MODEL))[t];
  const float x0 = bf2f(av.x), x1 = bf2f(av.y), x2 = bf2f(av.z), x3 = bf2f(av.w);
  float s = x0 + x1 + x2 + x3;
  float ss = x0 * x0 + x1 * x1 + x2 * x2 + x3 * x3;
  block_sum2(s, ss, sm);
  const float mu = s * (1.0f / D_MODEL);
  const float rs = rsqrtf(ss * (1.0f / D_MODEL) - mu * mu + 1e-5f);
  const ushort4 uv = ((const ushort4*)(mixed + (size_t)row * 4096))[t]; // user = cols 0..1023
  const float4 wv = ((const float4*)w)[t];
  const float4 bv = ((const float4*)b)[t];
  ushort4 o;
  o.x = f2bf(bf2f(uv.x) * ((x0 - mu) * rs * wv.x + bv.x));
  o.y = f2bf(bf2f(uv.y) * ((x1 - mu) * rs * wv.y + bv.y));
  o.z = f2bf(bf2f(uv.z) * ((x2 - mu) * rs * wv.z + bv.z));
  o.w = f2bf(bf2f(uv.w) * ((x3 - mu) * rs * wv.w + bv.w));
  ((ushort4*)(out + (size_t)row * D_MODEL))[t] = o;
}

// ---------------- ffn_in = rmsnorm(layer_output + layer_input) ----------------
__global__ __launch_bounds__(256)
void k_rms(const float* __restrict__ lo, const float* __restrict__ li,
           const float* __restrict__ w, u16* __restrict__ out) {
  __shared__ float sm[8];
  const int row = blockIdx.x, t = threadIdx.x;
  const float4 a = ((const float4*)(lo + (size_t)row * D_MODEL))[t];
  const float4 bq = ((const float4*)(li + (size_t)row * D_MODEL))[t];
  const float x0 = a.x + bq.x, x1 = a.y + bq.y, x2 = a.z + bq.z, x3 = a.w + bq.w;
  float ss = x0 * x0 + x1 * x1 + x2 * x2 + x3 * x3, dummy = 0.f;
  block_sum2(ss, dummy, sm);
  const float rs = rsqrtf(ss * (1.0f / D_MODEL) + 1e-5f);
  const float4 wv = ((const float4*)w)[t];
  ushort4 o;
  o.x = f2bf(x0 * rs * wv.x);
  o.y = f2bf(x1 * rs * wv.y);
  o.z = f2bf(x2 * rs * wv.z);
  o.w = f2bf(x3 * rs * wv.w);
  ((ushort4*)(out + (size_t)row * D_MODEL))[t] = o;
}

// ---------------- GEMM: C[M,N] = A[M,K] @ Bt[N,K]^T, bf16 in, fp32 acc ----------------
// Baseline block mapping (R19/R21-verified; XCD remap hurts here, R20).
// EPI_UVQK: fused qkvprep (user/Q->mixed, V->Vtc, K->Kc). EPI_SILUMUL: with
// 16-col-interleaved wt_1, ni even = a (w3), ni odd = b (w1), same lane:
// g[row][n0/2+wc*32+nj*16+l15] = silu(a)*b — k_silumul eliminated.
template <int EPI>
__global__ __launch_bounds__(256, 2)
void k_gemm(const u16* __restrict__ A, const u16* __restrict__ Bt,
            void* __restrict__ Cout, const float* __restrict__ bias,
            const float* __restrict__ addsrc,
            u16* __restrict__ kc, u16* __restrict__ vtc,
            int M, int N, int K) {
  __shared__ u16 As[128 * 64];
  __shared__ u16 Bs[128 * 64];
  const int t = threadIdx.x, lane = t & 63, w = t >> 6;
  const int l15 = lane & 15, l4 = lane >> 4;
  const int wr = w >> 1, wc = w & 1;
  const int m0 = blockIdx.x * 128, n0 = blockIdx.y * 128;
  const int lr = lane >> 3, lc = lane & 7;
  const int swz = (lc ^ lr) * 8; // pre-swizzled global k-offset (elements)

  f32x4_t acc[4][4];
  #pragma unroll
  for (int mi = 0; mi < 4; mi++)
    #pragma unroll
    for (int ni = 0; ni < 4; ni++) {
      acc[mi][ni][0] = 0.f; acc[mi][ni][1] = 0.f; acc[mi][ni][2] = 0.f; acc[mi][ni][3] = 0.f;
    }

  const u16* Ab = A + (size_t)m0 * K + swz;
  const u16* Bb = Bt + (size_t)n0 * K + swz;

  for (int kt = 0; kt < K; kt += 64) {
    #pragma unroll
    for (int j = 0; j < 4; j++) {
      const size_t rr = (size_t)((w * 4 + j) * 8 + lr);
      load_lds16(Ab + rr * K + kt, &As[(w * 4 + j) * 512]);
      load_lds16(Bb + rr * K + kt, &Bs[(w * 4 + j) * 512]);
    }
    __syncthreads();
    #pragma unroll
    for (int kk = 0; kk < 2; kk++) {
      bf16x8_t af[4], bf[4];
      #pragma unroll
      for (int mi = 0; mi < 4; mi++) {
        const int row = wr * 64 + mi * 16 + l15;
        const int cph = (kk * 4 + l4) ^ (row & 7);
        af[mi] = *(const bf16x8_t*)&As[row * 64 + cph * 8];
      }
      #pragma unroll
      for (int ni = 0; ni < 4; ni++) {
        const int row = wc * 64 + ni * 16 + l15;
        const int cph = (kk * 4 + l4) ^ (row & 7);
        bf[ni] = *(const bf16x8_t*)&Bs[row * 64 + cph * 8];
      }
      #pragma unroll
      for (int mi = 0; mi < 4; mi++)
        #pragma unroll
        for (int ni = 0; ni < 4; ni++)
          acc[mi][ni] = __builtin_amdgcn_mfma_f32_16x16x32_bf16(af[mi], bf[ni], acc[mi][ni], 0, 0, 0);
    }
    __syncthreads();
  }

  if constexpr (EPI == EPI_SILUMUL) {
    // interleaved wt_1: acc[mi][2nj] = a-cols, acc[mi][2nj+1] = matching b-cols
    #pragma unroll
    for (int mi = 0; mi < 4; mi++)
      #pragma unroll
      for (int nj = 0; nj < 2; nj++) {
        const int gcol = (n0 >> 1) + wc * 32 + nj * 16 + l15;
        #pragma unroll
        for (int r = 0; r < 4; r++) {
          const size_t row = (size_t)(m0 + wr * 64 + mi * 16 + l4 * 4 + r);
          ((u16*)Cout)[row * 1024 + gcol] =
              f2bf(silu_f(acc[mi][2 * nj][r]) * acc[mi][2 * nj + 1][r]);
        }
      }
  } else {
    #pragma unroll
    for (int mi = 0; mi < 4; mi++) {
      #pragma unroll
      for (int ni = 0; ni < 4; ni++) {
        const int col = n0 + wc * 64 + ni * 16 + l15;
        float bv = 0.f;
        if constexpr (EPI == EPI_UVQK) bv = bias[col];
        if constexpr (EPI == EPI_UVQK) {
          const int rowb = m0 + wr * 64 + mi * 16 + l4 * 4; // 4-aligned base row
          u16 c4[4];
          #pragma unroll
          for (int r = 0; r < 4; r++) c4[r] = f2bf(silu_f(acc[mi][ni][r] + bv));
          if (col < 1024 || (col >= 2048 && col < 3072)) {
            #pragma unroll
            for (int r = 0; r < 4; r++)
              ((u16*)Cout)[(size_t)(rowb + r) * N + col] = c4[r];
          } else if (col < 2048) {
            const int h = (col - 1024) >> 7, d = (col - 1024) & 127;
            const int bI = rowb >> 11, seqr = rowb & 2047;
            const size_t off = ((size_t)(bI * 8 + h) * 32 + (seqr >> 6)) * 8192 + d * 64 + (seqr & 63);
            *(ushort4*)&vtc[off] = *(const ushort4*)c4;
          } else {
            const int h = (col - 3072) >> 7, d = (col - 3072) & 127;
            const int bI = rowb >> 11, seqr = rowb & 2047;
            #pragma unroll
            for (int r = 0; r < 4; r++)
              kc[((size_t)(bI * 8 + h) * 2048 + seqr + r) * 128 + d] = c4[r];
          }
        } else {
          #pragma unroll
          for (int r = 0; r < 4; r++) {
            const size_t row = (size_t)(m0 + wr * 64 + mi * 16 + l4 * 4 + r);
            float v = acc[mi][ni][r];
            if constexpr (EPI == EPI_F32) {
              ((float*)Cout)[row * N + col] = v;
            } else {
              ((float*)Cout)[row * N + col] = v + addsrc[row * N + col];
            }
          }
        }
      }
    }
  }
}

// ---------------- split-K flash attention (R15 body, XCD-clustered bh) ----------
// grid: flat 768 blocks. XCD remap: v=(f%8)*96+f/8 (bijective) so each XCD's
// 96 blocks cover 4 heads -> Kc/Vtc working set 4MB = one XCD L2.
// Then v -> ci = v%24, bh = v/24; ci<16: qt=15-(ci>>1), ch=ci&1 (split qts 8..15);
// ci>=16: qt=23-ci single-chunk.
__global__ __launch_bounds__(256, 2)
void k_attn(const u16* __restrict__ mixed, const u16* __restrict__ Kc,
            const u16* __restrict__ Vtc, u16* __restrict__ attnb,
            u16* __restrict__ o_part, float* __restrict__ ml) {
  __shared__ u16 Ks[64 * 128];   // [key][d], 16B-granule swizzled by key&7
  __shared__ u16 Vts[128 * 64];  // [d][key], swizzled by (d&7)^((d>>3)&7)
  __shared__ u16 Ps[4 * 16 * 64];// per-wave P half-tiles (8KB)
  const int t = threadIdx.x, lane = t & 63, w = t >> 6;
  const int l15 = lane & 15, l4 = lane >> 4;
  const int f = blockIdx.x;
  const int v = (f & 7) * 96 + (f >> 3);   // XCD-clustering bijection (768 = 8*96)
  const int ci = v % 24, bh = v / 24;
  const int bI = bh >> 3, h = bh & 7;
  int qt, ch;
  if (ci < 16) { qt = 15 - (ci >> 1); ch = ci & 1; }
  else { qt = 23 - ci; ch = 0; }
  const bool split = (qt >= 8);
  const int qb = qt * 128;
  const int nt_all = 2 * qt + 2;
  const int t0 = (split && ch == 1) ? (qt + 1) : 0;
  const int t1 = (split && ch == 0) ? (qt + 1) : nt_all;

  const u16* base = mixed + (size_t)bI * SEQ * 4096;
  const int qcol = 2 * D_MODEL + h * HDIM;
  const int qrow0 = qb + w * 32;
  const u16* Kh = Kc + (size_t)bh * SEQ * 128;
  const u16* Vh = Vtc + (size_t)bh * 32 * 8192;

  const int nk = lane;

  bf16x8_t qf[2][4];
  #pragma unroll
  for (int mi = 0; mi < 2; mi++) {
    const u16* qp = base + (size_t)(qrow0 + mi * 16 + l15) * 4096 + qcol + l4 * 8;
    #pragma unroll
    for (int ks = 0; ks < 4; ks++) qf[mi][ks] = *(const bf16x8_t*)(qp + ks * 32);
  }

  f32x4_t o[2][8];
  #pragma unroll
  for (int mi = 0; mi < 2; mi++)
    #pragma unroll
    for (int df = 0; df < 8; df++) { o[mi][df][0] = 0.f; o[mi][df][1] = 0.f; o[mi][df][2] = 0.f; o[mi][df][3] = 0.f; }
  float mrun[2][4], lrun[2][4];
  #pragma unroll
  for (int mi = 0; mi < 2; mi++)
    #pragma unroll
    for (int r = 0; r < 4; r++) { mrun[mi][r] = -1e30f; lrun[mi][r] = 0.f; }

  const float alpha = 0.08838834764831845f; // 1/sqrt(128)

  // ---- stage(tile): 8 global_load_lds per thread into single buffers ----
  auto stage = [&](int tile) {
    const u16* Kt = Kh + (size_t)(tile * 64) * 128;
    const u16* Vt = Vh + (size_t)tile * 8192;
    #pragma unroll
    for (int j = 0; j < 4; j++) {
      const int slot = j * 4 + w;
      const int kr = slot * 4 + (nk >> 4), gk = nk & 15;
      load_lds16(Kt + kr * 128 + ((gk ^ (kr & 7)) * 8), &Ks[slot * 512]);
      const int d = slot * 8 + (nk >> 3), gv = nk & 7;
      load_lds16(Vt + d * 64 + ((gv ^ (d & 7) ^ ((d >> 3) & 7)) * 8), &Vts[slot * 512]);
    }
  };

  for (int it = t0; it < t1; it++) {
    const int kb = it * 64;
    stage(it);
    __syncthreads(); // drain stage — covered by other resident blocks

    const bool active = (kb <= qrow0 + 31);
    const bool needmask = (kb + 63 > qrow0);
    if (active) {
      f32x4_t s[2][4];
      #pragma unroll
      for (int mi = 0; mi < 2; mi++)
        #pragma unroll
        for (int ni = 0; ni < 4; ni++) { s[mi][ni][0] = 0.f; s[mi][ni][1] = 0.f; s[mi][ni][2] = 0.f; s[mi][ni][3] = 0.f; }
      #pragma unroll
      for (int ks = 0; ks < 4; ks++) {
        bf16x8_t kf[4];
        #pragma unroll
        for (int ni = 0; ni < 4; ni++) {
          const int key = ni * 16 + l15;
          const int cph = (ks * 4 + l4) ^ (key & 7);
          kf[ni] = *(const bf16x8_t*)&Ks[key * 128 + cph * 8];
        }
        #pragma unroll
        for (int mi = 0; mi < 2; mi++)
          #pragma unroll
          for (int ni = 0; ni < 4; ni++)
            s[mi][ni] = __builtin_amdgcn_mfma_f32_16x16x32_bf16(qf[mi][ks], kf[ni], s[mi][ni], 0, 0, 0);
      }
      #pragma unroll
      for (int mi = 0; mi < 2; mi++) {
        #pragma unroll
        for (int r = 0; r < 4; r++) {
          const int qr = qrow0 + mi * 16 + l4 * 4 + r;
          float mx = -1e30f;
          #pragma unroll
          for (int ni = 0; ni < 4; ni++) {
            float v2 = s[mi][ni][r] * alpha;
            if (needmask) {
              const int key = kb + ni * 16 + l15;
              if (key > qr) v2 = -1e30f;
            }
            s[mi][ni][r] = v2;
            mx = fmaxf(mx, v2);
          }
          #pragma unroll
          for (int off = 1; off < 16; off <<= 1) mx = fmaxf(mx, __shfl_xor(mx, off, 64));
          const float mnew = fmaxf(mrun[mi][r], mx);
          const float fsc = __expf(mrun[mi][r] - mnew);
          mrun[mi][r] = mnew;
          lrun[mi][r] *= fsc;
          #pragma unroll
          for (int df = 0; df < 8; df++) o[mi][df][r] *= fsc;
          float ls = 0.f;
          #pragma unroll
          for (int ni = 0; ni < 4; ni++) {
            const float p = __expf(s[mi][ni][r] - mnew);
            s[mi][ni][r] = p;
            ls += p;
          }
          #pragma unroll
          for (int off = 1; off < 16; off <<= 1) ls += __shfl_xor(ls, off, 64);
          lrun[mi][r] += ls;
        }
        // P half-tile write (per-wave private region; wave-local ordering)
        #pragma unroll
        for (int ni = 0; ni < 4; ni++)
          #pragma unroll
          for (int r = 0; r < 4; r++) {
            const int pr = l4 * 4 + r;
            const int pc = ni * 16 + l15;
            Ps[w * 1024 + pr * 64 + (((pc >> 3) ^ (pr & 7)) * 8) + (pc & 7)] = f2bf(s[mi][ni][r]);
          }
        // PV for this half
        #pragma unroll
        for (int ks2 = 0; ks2 < 2; ks2++) {
          bf16x8_t pa;
          {
            const int pr = l15;
            const int cph = (ks2 * 4 + l4) ^ (pr & 7);
            pa = *(const bf16x8_t*)&Ps[w * 1024 + pr * 64 + cph * 8];
          }
          #pragma unroll
          for (int df = 0; df < 8; df++) {
            const int d = df * 16 + l15;
            const int cph = (ks2 * 4 + l4) ^ (d & 7) ^ ((d >> 3) & 7);
            const bf16x8_t vb = *(const bf16x8_t*)&Vts[d * 64 + cph * 8];
            o[mi][df] = __builtin_amdgcn_mfma_f32_16x16x32_bf16(pa, vb, o[mi][df], 0, 0, 0);
          }
        }
      }
    }
    __syncthreads(); // reads of Ks/Vts done before next tile's stage
  }

  if (!split) {
    #pragma unroll
    for (int mi = 0; mi < 2; mi++) {
      #pragma unroll
      for (int r = 0; r < 4; r++) {
        const float inv = 1.0f / lrun[mi][r];
        const size_t row = (size_t)bI * SEQ + qrow0 + mi * 16 + l4 * 4 + r;
        #pragma unroll
        for (int df = 0; df < 8; df++)
          attnb[row * D_MODEL + h * HDIM + df * 16 + l15] = f2bf(o[mi][df][r] * inv);
      }
    }
  } else {
    const int sl = bh * 8 + (qt - 8);
    #pragma unroll
    for (int mi = 0; mi < 2; mi++) {
      #pragma unroll
      for (int r = 0; r < 4; r++) {
        const int pr = w * 32 + mi * 16 + l4 * 4 + r;
        if (l15 == 0) {
          ml[sl * 512 + ch * 256 + pr] = mrun[mi][r];
          ml[sl * 512 + ch * 256 + 128 + pr] = lrun[mi][r];
        }
        if (ch == 0) {
          const size_t row = (size_t)bI * SEQ + qb + pr;
          #pragma unroll
          for (int df = 0; df < 8; df++)
            attnb[row * D_MODEL + h * HDIM + df * 16 + l15] = f2bf(o[mi][df][r]);
        } else {
          #pragma unroll
          for (int df = 0; df < 8; df++)
            o_part[(size_t)sl * 16384 + pr * 128 + df * 16 + l15] = f2bf(o[mi][df][r]);
        }
      }
    }
  }
}

// ---------------- combine split chunks for qt 8..15 ----------------
// grid: (8, 32). 256 threads: 2 per row, 64 d each.
__global__ __launch_bounds__(256)
void k_combine(const u16* __restrict__ o_part, const float* __restrict__ ml,
               u16* __restrict__ attnb) {
  const int qti = blockIdx.x, bh = blockIdx.y;
  const int bI = bh >> 3, h = bh & 7;
  const int t = threadIdx.x;
  const int pr = t >> 1, half = t & 1;
  const int sl = bh * 8 + qti;
  const float m0 = ml[sl * 512 + pr];
  const float l0 = ml[sl * 512 + 128 + pr];
  const float m1 = ml[sl * 512 + 256 + pr];
  const float l1 = ml[sl * 512 + 384 + pr];
  const float M = fmaxf(m0, m1);
  const float w0 = __expf(m0 - M), w1 = __expf(m1 - M);
  const float inv = 1.0f / (w0 * l0 + w1 * l1);
  const float c0 = w0 * inv, c1 = w1 * inv;
  const size_t row = (size_t)bI * SEQ + (8 + qti) * 128 + pr;
  u16* ap = attnb + row * D_MODEL + h * HDIM + half * 64;
  const u16* pp = o_part + (size_t)sl * 16384 + pr * 128 + half * 64;
  #pragma unroll
  for (int j = 0; j < 8; j++) {
    u16 a[8], b[8], c[8];
    *(uint4*)a = ((const uint4*)ap)[j];
    *(uint4*)b = ((const uint4*)pp)[j];
    #pragma unroll
    for (int i = 0; i < 8; i++) c[i] = f2bf(c0 * bf2f(a[i]) + c1 * bf2f(b[i]));
    ((uint4*)ap)[j] = *(const uint4*)c;
  }
}

extern "C" void kernel_launch(void* const* d_in, const int* in_sizes, int n_in,
                              void* d_out, int out_size, void* d_ws, size_t ws_size,
                              hipStream_t stream) {
  (void)in_sizes; (void)n_in; (void)out_size; (void)ws_size;
  const float* layer_input = (const float*)d_in[0];
  // d_in[1] = positions (unused by reference)
  const float* ln_in_w  = (const float*)d_in[2];
  const float* ln_in_b  = (const float*)d_in[3];
  const float* W_uvqk   = (const float*)d_in[4];
  const float* b_uvqk   = (const float*)d_in[5];
  const float* ln_out_w = (const float*)d_in[6];
  const float* ln_out_b = (const float*)d_in[7];
  const float* W_proj   = (const float*)d_in[8];
  const float* rms_w    = (const float*)d_in[9];
  const float* W1       = (const float*)d_in[10];
  const float* W2       = (const float*)d_in[11];
  float* out = (float*)d_out;

  char* ws = (char*)d_ws;
  u16* buf0    = (u16*)(ws);                          // 16 MB: normed/gated/ffn_in
  u16* mixed   = (u16*)(ws + ((size_t)16 << 20));     // 64 MB: uvqk out; later g
  u16* attnb   = (u16*)(ws + ((size_t)80 << 20));     // 16 MB
  float* lout  = (float*)(ws + ((size_t)96 << 20));   // 32 MB: layer_output fp32 (post-attn)
  u16* Kc      = (u16*)(ws + ((size_t)96 << 20));     // 16 MB dense K (dead before proj)
  u16* Vtc     = (u16*)(ws + ((size_t)112 << 20));    // 16 MB dense V^T tiles (dead before proj)
  u16* wt_uvqk = (u16*)(ws + ((size_t)128 << 20));    // 8 MB
  u16* wt_proj = (u16*)(ws + ((size_t)136 << 20));    // 2 MB
  u16* wt_1    = (u16*)(ws + ((size_t)138 << 20));    // 4 MB (16-col-interleaved)
  u16* wt_2    = (u16*)(ws + ((size_t)142 << 20));    // 2 MB
  // split-K scratch lives in d_out (fully overwritten by the final GEMM):
  u16* o_part  = (u16*)d_out;                          // 8 MB partials (256 slots x 32KB)
  float* ml    = (float*)((char*)d_out + ((size_t)20 << 20)); // 512 KB m/l

  k_wconv<0><<<dim3(128, 32), 256, 0, stream>>>(W_uvqk, wt_uvqk, 1024, 4096);
  k_wconv<0><<<dim3(32, 32), 256, 0, stream>>>(W_proj, wt_proj, 1024, 1024);
  k_wconv<1><<<dim3(64, 32), 256, 0, stream>>>(W1, wt_1, 1024, 2048);
  k_wconv<0><<<dim3(32, 32), 256, 0, stream>>>(W2, wt_2, 1024, 1024);

  k_ln_in<<<NROWS, 256, 0, stream>>>(layer_input, ln_in_w, ln_in_b, buf0);
  k_gemm<EPI_UVQK><<<dim3(64, 32), 256, 0, stream>>>(buf0, wt_uvqk, mixed, b_uvqk, nullptr, Kc, Vtc, NROWS, 4096, 1024);
  k_attn<<<768, 256, 0, stream>>>(mixed, Kc, Vtc, attnb, o_part, ml);
  k_combine<<<dim3(8, 32), 256, 0, stream>>>(o_part, ml, attnb);
  k_gated<<<NROWS, 256, 0, stream>>>(attnb, mixed, ln_out_w, ln_out_b, buf0);
  k_gemm<EPI_F32><<<dim3(64, 8), 256, 0, stream>>>(buf0, wt_proj, lout, nullptr, nullptr, nullptr, nullptr, NROWS, 1024, 1024);
  k_rms<<<NROWS, 256, 0, stream>>>(lout, layer_input, rms_w, buf0);
  k_gemm<EPI_SILUMUL><<<dim3(64, 16), 256, 0, stream>>>(buf0, wt_1, mixed, nullptr, nullptr, nullptr, nullptr, NROWS, 2048, 1024);
  k_gemm<EPI_ADD_F32><<<dim3(64, 8), 256, 0, stream>>>(mixed, wt_2, out, nullptr, lout, nullptr, nullptr, NROWS, 1024, 1024);
}

// Round 24
// 349.083 us; speedup vs baseline: 1.1541x; 1.0330x over previous
//
#include <hip/hip_runtime.h>
#include <stdint.h>

typedef unsigned short u16;
typedef __bf16 bf16x8_t __attribute__((ext_vector_type(8)));
typedef float f32x4_t __attribute__((ext_vector_type(4)));

#define D_MODEL 1024
#define SEQ 2048
#define BATCH 4
#define NROWS (BATCH * SEQ)
#define HDIM 128

constexpr int EPI_UVQK = 0;    // silu+bias; route user/Q->mixed, V->Vtc, K->Kc
constexpr int EPI_BF16O = 1;   // proj: layer_output as bf16
constexpr int EPI_SILUMUL = 2; // interleaved W1: g = silu(a)*b directly
constexpr int EPI_ADD_BF16 = 3;// W2: out = acc + bf2f(addsrc16) (fp32 out)

__device__ __forceinline__ float bf2f(u16 u) {
  union { unsigned int i; float f; } v; v.i = ((unsigned int)u) << 16; return v.f;
}
__device__ __forceinline__ u16 f2bf(float f) {
  union { float f; unsigned int i; } v; v.f = f;
  unsigned int r = (v.i + 0x7FFFu + ((v.i >> 16) & 1u)) >> 16;
  return (u16)r;
}
__device__ __forceinline__ float silu_f(float x) { return x / (1.0f + __expf(-x)); }

// async global->LDS, 16B per lane. LDS dest must be wave-uniform base (HW adds lane*16).
__device__ __forceinline__ void load_lds16(const void* g, void* l) {
  auto gp = (const __attribute__((address_space(1))) char*)(uintptr_t)g;
  auto lp = (__attribute__((address_space(3))) char*)(uint32_t)(uintptr_t)l;
  __builtin_amdgcn_global_load_lds(gp, lp, 16, 0, 0);
}

__device__ __forceinline__ void block_sum2(float& a, float& b, float* sm) {
  #pragma unroll
  for (int off = 32; off > 0; off >>= 1) {
    a += __shfl_xor(a, off, 64);
    b += __shfl_xor(b, off, 64);
  }
  const int w = threadIdx.x >> 6;
  if ((threadIdx.x & 63) == 0) { sm[w] = a; sm[4 + w] = b; }
  __syncthreads();
  a = sm[0] + sm[1] + sm[2] + sm[3];
  b = sm[4] + sm[5] + sm[6] + sm[7];
}

// ---------------- weight fp32 [K][N] -> bf16 [N][K] (transposed) ----------------
// ILV=1 (W1): 16-col-group interleave so silu(a)*b pairs share a lane.
template <int ILV>
__global__ __launch_bounds__(256)
void k_wconv(const float* __restrict__ W, u16* __restrict__ Wt, int K, int N) {
  __shared__ float tile[32][33];
  const int n0 = blockIdx.x * 32, k0 = blockIdx.y * 32;
  const int tx = threadIdx.x & 31, ty = threadIdx.x >> 5;
  #pragma unroll
  for (int i = 0; i < 4; i++)
    tile[ty + 8 * i][tx] = W[(size_t)(k0 + ty + 8 * i) * N + n0 + tx];
  __syncthreads();
  #pragma unroll
  for (int i = 0; i < 4; i++) {
    const int nlog = n0 + ty + 8 * i;
    int rowp;
    if (ILV == 0) rowp = nlog;
    else rowp = (nlog < 1024) ? (32 * (nlog >> 4) + (nlog & 15))
                              : (32 * ((nlog - 1024) >> 4) + 16 + ((nlog - 1024) & 15));
    Wt[(size_t)rowp * K + k0 + tx] = f2bf(tile[tx][ty + 8 * i]);
  }
}

// ---------------- input layernorm: fp32 [row][1024] -> bf16 ----------------
__global__ __launch_bounds__(256)
void k_ln_in(const float* __restrict__ X, const float* __restrict__ w,
             const float* __restrict__ b, u16* __restrict__ Y) {
  __shared__ float sm[8];
  const int row = blockIdx.x, t = threadIdx.x;
  const float4 v = ((const float4*)(X + (size_t)row * D_MODEL))[t];
  float s = v.x + v.y + v.z + v.w;
  float ss = v.x * v.x + v.y * v.y + v.z * v.z + v.w * v.w;
  block_sum2(s, ss, sm);
  const float mu = s * (1.0f / D_MODEL);
  const float var = ss * (1.0f / D_MODEL) - mu * mu;
  const float rs = rsqrtf(var + 1e-5f);
  const float4 wv = ((const float4*)w)[t];
  const float4 bv = ((const float4*)b)[t];
  ushort4 o;
  o.x = f2bf((v.x - mu) * rs * wv.x + bv.x);
  o.y = f2bf((v.y - mu) * rs * wv.y + bv.y);
  o.z = f2bf((v.z - mu) * rs * wv.z + bv.z);
  o.w = f2bf((v.w - mu) * rs * wv.w + bv.w);
  ((ushort4*)(Y + (size_t)row * D_MODEL))[t] = o;
}

// ---------------- parallel = user * layernorm(merged attn) ----------------
// Fuses the split-K combine: for seq>=1024 rows, merge ch0 (attnb, unnorm)
// with ch1 (o_part) using (m,l) in fp32 BEFORE the LN stats.
__global__ __launch_bounds__(256)
void k_gated(const u16* __restrict__ attn, const u16* __restrict__ mixed,
             const float* __restrict__ w, const float* __restrict__ b,
             const u16* __restrict__ o_part, const float* __restrict__ ml,
             u16* __restrict__ out) {
  __shared__ float sm[8];
  const int row = blockIdx.x, t = threadIdx.x;
  const int bI = row >> 11, seq = row & 2047;
  const ushort4 av = ((const ushort4*)(attn + (size_t)row * D_MODEL))[t];
  float x0, x1, x2, x3;
  if (seq < 1024) {
    x0 = bf2f(av.x); x1 = bf2f(av.y); x2 = bf2f(av.z); x3 = bf2f(av.w);
  } else {
    const int qti = (seq >> 7) - 8, pr = seq & 127;
    const int h = t >> 5;
    const int sl = (bI * 8 + h) * 8 + qti;
    const float m0 = ml[sl * 512 + pr];
    const float l0 = ml[sl * 512 + 128 + pr];
    const float m1 = ml[sl * 512 + 256 + pr];
    const float l1 = ml[sl * 512 + 384 + pr];
    const float M = fmaxf(m0, m1);
    const float w0 = __expf(m0 - M), w1 = __expf(m1 - M);
    const float inv = 1.0f / (w0 * l0 + w1 * l1);
    const float c0 = w0 * inv, c1 = w1 * inv;
    const ushort4 bv4 = *(const ushort4*)&o_part[(size_t)sl * 16384 + pr * 128 + ((4 * t) & 127)];
    x0 = c0 * bf2f(av.x) + c1 * bf2f(bv4.x);
    x1 = c0 * bf2f(av.y) + c1 * bf2f(bv4.y);
    x2 = c0 * bf2f(av.z) + c1 * bf2f(bv4.z);
    x3 = c0 * bf2f(av.w) + c1 * bf2f(bv4.w);
  }
  float s = x0 + x1 + x2 + x3;
  float ss = x0 * x0 + x1 * x1 + x2 * x2 + x3 * x3;
  block_sum2(s, ss, sm);
  const float mu = s * (1.0f / D_MODEL);
  const float rs = rsqrtf(ss * (1.0f / D_MODEL) - mu * mu + 1e-5f);
  const ushort4 uv = ((const ushort4*)(mixed + (size_t)row * 4096))[t]; // user = cols 0..1023
  const float4 wv = ((const float4*)w)[t];
  const float4 bv = ((const float4*)b)[t];
  ushort4 o;
  o.x = f2bf(bf2f(uv.x) * ((x0 - mu) * rs * wv.x + bv.x));
  o.y = f2bf(bf2f(uv.y) * ((x1 - mu) * rs * wv.y + bv.y));
  o.z = f2bf(bf2f(uv.z) * ((x2 - mu) * rs * wv.z + bv.z));
  o.w = f2bf(bf2f(uv.w) * ((x3 - mu) * rs * wv.w + bv.w));
  ((ushort4*)(out + (size_t)row * D_MODEL))[t] = o;
}

// ---------------- ffn_in = rmsnorm(layer_output(bf16) + layer_input) ----------------
__global__ __launch_bounds__(256)
void k_rms(const u16* __restrict__ lo, const float* __restrict__ li,
           const float* __restrict__ w, u16* __restrict__ out) {
  __shared__ float sm[8];
  const int row = blockIdx.x, t = threadIdx.x;
  const ushort4 a = ((const ushort4*)(lo + (size_t)row * D_MODEL))[t];
  const float4 bq = ((const float4*)(li + (size_t)row * D_MODEL))[t];
  const float x0 = bf2f(a.x) + bq.x, x1 = bf2f(a.y) + bq.y;
  const float x2 = bf2f(a.z) + bq.z, x3 = bf2f(a.w) + bq.w;
  float ss = x0 * x0 + x1 * x1 + x2 * x2 + x3 * x3, dummy = 0.f;
  block_sum2(ss, dummy, sm);
  const float rs = rsqrtf(ss * (1.0f / D_MODEL) + 1e-5f);
  const float4 wv = ((const float4*)w)[t];
  ushort4 o;
  o.x = f2bf(x0 * rs * wv.x);
  o.y = f2bf(x1 * rs * wv.y);
  o.z = f2bf(x2 * rs * wv.z);
  o.w = f2bf(x3 * rs * wv.w);
  ((ushort4*)(out + (size_t)row * D_MODEL))[t] = o;
}

// ---------------- GEMM: C[M,N] = A[M,K] @ Bt[N,K]^T, bf16 in, fp32 acc ----------------
// Baseline block mapping (R19/R21-verified; XCD remap hurts here, R20).
// EPI_UVQK: fused qkvprep. EPI_SILUMUL: fused silu-mul (interleaved wt_1).
// EPI_BF16O: bf16 layer_output. EPI_ADD_BF16: out = acc + bf2f(addsrc16[kc]).
template <int EPI>
__global__ __launch_bounds__(256, 2)
void k_gemm(const u16* __restrict__ A, const u16* __restrict__ Bt,
            void* __restrict__ Cout, const float* __restrict__ bias,
            const float* __restrict__ addsrc,
            u16* __restrict__ kc, u16* __restrict__ vtc,
            int M, int N, int K) {
  __shared__ u16 As[128 * 64];
  __shared__ u16 Bs[128 * 64];
  const int t = threadIdx.x, lane = t & 63, w = t >> 6;
  const int l15 = lane & 15, l4 = lane >> 4;
  const int wr = w >> 1, wc = w & 1;
  const int m0 = blockIdx.x * 128, n0 = blockIdx.y * 128;
  const int lr = lane >> 3, lc = lane & 7;
  const int swz = (lc ^ lr) * 8; // pre-swizzled global k-offset (elements)

  f32x4_t acc[4][4];
  #pragma unroll
  for (int mi = 0; mi < 4; mi++)
    #pragma unroll
    for (int ni = 0; ni < 4; ni++) {
      acc[mi][ni][0] = 0.f; acc[mi][ni][1] = 0.f; acc[mi][ni][2] = 0.f; acc[mi][ni][3] = 0.f;
    }

  const u16* Ab = A + (size_t)m0 * K + swz;
  const u16* Bb = Bt + (size_t)n0 * K + swz;

  for (int kt = 0; kt < K; kt += 64) {
    #pragma unroll
    for (int j = 0; j < 4; j++) {
      const size_t rr = (size_t)((w * 4 + j) * 8 + lr);
      load_lds16(Ab + rr * K + kt, &As[(w * 4 + j) * 512]);
      load_lds16(Bb + rr * K + kt, &Bs[(w * 4 + j) * 512]);
    }
    __syncthreads();
    #pragma unroll
    for (int kk = 0; kk < 2; kk++) {
      bf16x8_t af[4], bf[4];
      #pragma unroll
      for (int mi = 0; mi < 4; mi++) {
        const int row = wr * 64 + mi * 16 + l15;
        const int cph = (kk * 4 + l4) ^ (row & 7);
        af[mi] = *(const bf16x8_t*)&As[row * 64 + cph * 8];
      }
      #pragma unroll
      for (int ni = 0; ni < 4; ni++) {
        const int row = wc * 64 + ni * 16 + l15;
        const int cph = (kk * 4 + l4) ^ (row & 7);
        bf[ni] = *(const bf16x8_t*)&Bs[row * 64 + cph * 8];
      }
      #pragma unroll
      for (int mi = 0; mi < 4; mi++)
        #pragma unroll
        for (int ni = 0; ni < 4; ni++)
          acc[mi][ni] = __builtin_amdgcn_mfma_f32_16x16x32_bf16(af[mi], bf[ni], acc[mi][ni], 0, 0, 0);
    }
    __syncthreads();
  }

  if constexpr (EPI == EPI_SILUMUL) {
    // interleaved wt_1: acc[mi][2nj] = a-cols, acc[mi][2nj+1] = matching b-cols
    #pragma unroll
    for (int mi = 0; mi < 4; mi++)
      #pragma unroll
      for (int nj = 0; nj < 2; nj++) {
        const int gcol = (n0 >> 1) + wc * 32 + nj * 16 + l15;
        #pragma unroll
        for (int r = 0; r < 4; r++) {
          const size_t row = (size_t)(m0 + wr * 64 + mi * 16 + l4 * 4 + r);
          ((u16*)Cout)[row * 1024 + gcol] =
              f2bf(silu_f(acc[mi][2 * nj][r]) * acc[mi][2 * nj + 1][r]);
        }
      }
  } else {
    #pragma unroll
    for (int mi = 0; mi < 4; mi++) {
      #pragma unroll
      for (int ni = 0; ni < 4; ni++) {
        const int col = n0 + wc * 64 + ni * 16 + l15;
        float bv = 0.f;
        if constexpr (EPI == EPI_UVQK) bv = bias[col];
        if constexpr (EPI == EPI_UVQK) {
          const int rowb = m0 + wr * 64 + mi * 16 + l4 * 4; // 4-aligned base row
          u16 c4[4];
          #pragma unroll
          for (int r = 0; r < 4; r++) c4[r] = f2bf(silu_f(acc[mi][ni][r] + bv));
          if (col < 1024 || (col >= 2048 && col < 3072)) {
            #pragma unroll
            for (int r = 0; r < 4; r++)
              ((u16*)Cout)[(size_t)(rowb + r) * N + col] = c4[r];
          } else if (col < 2048) {
            const int h = (col - 1024) >> 7, d = (col - 1024) & 127;
            const int bI = rowb >> 11, seqr = rowb & 2047;
            const size_t off = ((size_t)(bI * 8 + h) * 32 + (seqr >> 6)) * 8192 + d * 64 + (seqr & 63);
            *(ushort4*)&vtc[off] = *(const ushort4*)c4;
          } else {
            const int h = (col - 3072) >> 7, d = (col - 3072) & 127;
            const int bI = rowb >> 11, seqr = rowb & 2047;
            #pragma unroll
            for (int r = 0; r < 4; r++)
              kc[((size_t)(bI * 8 + h) * 2048 + seqr + r) * 128 + d] = c4[r];
          }
        } else {
          #pragma unroll
          for (int r = 0; r < 4; r++) {
            const size_t row = (size_t)(m0 + wr * 64 + mi * 16 + l4 * 4 + r);
            float v = acc[mi][ni][r];
            if constexpr (EPI == EPI_BF16O) {
              ((u16*)Cout)[row * N + col] = f2bf(v);
            } else { // EPI_ADD_BF16: addsrc16 passed via kc
              ((float*)Cout)[row * N + col] = v + bf2f(kc[row * N + col]);
            }
          }
        }
      }
    }
  }
}

// ---------------- split-K flash attention (R15 body, XCD-clustered bh) ----------
// grid: flat 768 blocks. XCD remap: v=(f%8)*96+f/8 (bijective) so each XCD's
// 96 blocks cover 4 heads -> Kc/Vtc working set 4MB = one XCD L2.
__global__ __launch_bounds__(256, 2)
void k_attn(const u16* __restrict__ mixed, const u16* __restrict__ Kc,
            const u16* __restrict__ Vtc, u16* __restrict__ attnb,
            u16* __restrict__ o_part, float* __restrict__ ml) {
  __shared__ u16 Ks[64 * 128];   // [key][d], 16B-granule swizzled by key&7
  __shared__ u16 Vts[128 * 64];  // [d][key], swizzled by (d&7)^((d>>3)&7)
  __shared__ u16 Ps[4 * 16 * 64];// per-wave P half-tiles (8KB)
  const int t = threadIdx.x, lane = t & 63, w = t >> 6;
  const int l15 = lane & 15, l4 = lane >> 4;
  const int f = blockIdx.x;
  const int v = (f & 7) * 96 + (f >> 3);   // XCD-clustering bijection (768 = 8*96)
  const int ci = v % 24, bh = v / 24;
  const int bI = bh >> 3, h = bh & 7;
  int qt, ch;
  if (ci < 16) { qt = 15 - (ci >> 1); ch = ci & 1; }
  else { qt = 23 - ci; ch = 0; }
  const bool split = (qt >= 8);
  const int qb = qt * 128;
  const int nt_all = 2 * qt + 2;
  const int t0 = (split && ch == 1) ? (qt + 1) : 0;
  const int t1 = (split && ch == 0) ? (qt + 1) : nt_all;

  const u16* base = mixed + (size_t)bI * SEQ * 4096;
  const int qcol = 2 * D_MODEL + h * HDIM;
  const int qrow0 = qb + w * 32;
  const u16* Kh = Kc + (size_t)bh * SEQ * 128;
  const u16* Vh = Vtc + (size_t)bh * 32 * 8192;

  const int nk = lane;

  bf16x8_t qf[2][4];
  #pragma unroll
  for (int mi = 0; mi < 2; mi++) {
    const u16* qp = base + (size_t)(qrow0 + mi * 16 + l15) * 4096 + qcol + l4 * 8;
    #pragma unroll
    for (int ks = 0; ks < 4; ks++) qf[mi][ks] = *(const bf16x8_t*)(qp + ks * 32);
  }

  f32x4_t o[2][8];
  #pragma unroll
  for (int mi = 0; mi < 2; mi++)
    #pragma unroll
    for (int df = 0; df < 8; df++) { o[mi][df][0] = 0.f; o[mi][df][1] = 0.f; o[mi][df][2] = 0.f; o[mi][df][3] = 0.f; }
  float mrun[2][4], lrun[2][4];
  #pragma unroll
  for (int mi = 0; mi < 2; mi++)
    #pragma unroll
    for (int r = 0; r < 4; r++) { mrun[mi][r] = -1e30f; lrun[mi][r] = 0.f; }

  const float alpha = 0.08838834764831845f; // 1/sqrt(128)

  // ---- stage(tile): 8 global_load_lds per thread into single buffers ----
  auto stage = [&](int tile) {
    const u16* Kt = Kh + (size_t)(tile * 64) * 128;
    const u16* Vt = Vh + (size_t)tile * 8192;
    #pragma unroll
    for (int j = 0; j < 4; j++) {
      const int slot = j * 4 + w;
      const int kr = slot * 4 + (nk >> 4), gk = nk & 15;
      load_lds16(Kt + kr * 128 + ((gk ^ (kr & 7)) * 8), &Ks[slot * 512]);
      const int d = slot * 8 + (nk >> 3), gv = nk & 7;
      load_lds16(Vt + d * 64 + ((gv ^ (d & 7) ^ ((d >> 3) & 7)) * 8), &Vts[slot * 512]);
    }
  };

  for (int it = t0; it < t1; it++) {
    const int kb = it * 64;
    stage(it);
    __syncthreads(); // drain stage — covered by other resident blocks

    const bool active = (kb <= qrow0 + 31);
    const bool needmask = (kb + 63 > qrow0);
    if (active) {
      f32x4_t s[2][4];
      #pragma unroll
      for (int mi = 0; mi < 2; mi++)
        #pragma unroll
        for (int ni = 0; ni < 4; ni++) { s[mi][ni][0] = 0.f; s[mi][ni][1] = 0.f; s[mi][ni][2] = 0.f; s[mi][ni][3] = 0.f; }
      #pragma unroll
      for (int ks = 0; ks < 4; ks++) {
        bf16x8_t kf[4];
        #pragma unroll
        for (int ni = 0; ni < 4; ni++) {
          const int key = ni * 16 + l15;
          const int cph = (ks * 4 + l4) ^ (key & 7);
          kf[ni] = *(const bf16x8_t*)&Ks[key * 128 + cph * 8];
        }
        #pragma unroll
        for (int mi = 0; mi < 2; mi++)
          #pragma unroll
          for (int ni = 0; ni < 4; ni++)
            s[mi][ni] = __builtin_amdgcn_mfma_f32_16x16x32_bf16(qf[mi][ks], kf[ni], s[mi][ni], 0, 0, 0);
      }
      #pragma unroll
      for (int mi = 0; mi < 2; mi++) {
        #pragma unroll
        for (int r = 0; r < 4; r++) {
          const int qr = qrow0 + mi * 16 + l4 * 4 + r;
          float mx = -1e30f;
          #pragma unroll
          for (int ni = 0; ni < 4; ni++) {
            float v2 = s[mi][ni][r] * alpha;
            if (needmask) {
              const int key = kb + ni * 16 + l15;
              if (key > qr) v2 = -1e30f;
            }
            s[mi][ni][r] = v2;
            mx = fmaxf(mx, v2);
          }
          #pragma unroll
          for (int off = 1; off < 16; off <<= 1) mx = fmaxf(mx, __shfl_xor(mx, off, 64));
          const float mnew = fmaxf(mrun[mi][r], mx);
          const float fsc = __expf(mrun[mi][r] - mnew);
          mrun[mi][r] = mnew;
          lrun[mi][r] *= fsc;
          #pragma unroll
          for (int df = 0; df < 8; df++) o[mi][df][r] *= fsc;
          float ls = 0.f;
          #pragma unroll
          for (int ni = 0; ni < 4; ni++) {
            const float p = __expf(s[mi][ni][r] - mnew);
            s[mi][ni][r] = p;
            ls += p;
          }
          #pragma unroll
          for (int off = 1; off < 16; off <<= 1) ls += __shfl_xor(ls, off, 64);
          lrun[mi][r] += ls;
        }
        // P half-tile write (per-wave private region; wave-local ordering)
        #pragma unroll
        for (int ni = 0; ni < 4; ni++)
          #pragma unroll
          for (int r = 0; r < 4; r++) {
            const int pr = l4 * 4 + r;
            const int pc = ni * 16 + l15;
            Ps[w * 1024 + pr * 64 + (((pc >> 3) ^ (pr & 7)) * 8) + (pc & 7)] = f2bf(s[mi][ni][r]);
          }
        // PV for this half
        #pragma unroll
        for (int ks2 = 0; ks2 < 2; ks2++) {
          bf16x8_t pa;
          {
            const int pr = l15;
            const int cph = (ks2 * 4 + l4) ^ (pr & 7);
            pa = *(const bf16x8_t*)&Ps[w * 1024 + pr * 64 + cph * 8];
          }
          #pragma unroll
          for (int df = 0; df < 8; df++) {
            const int d = df * 16 + l15;
            const int cph = (ks2 * 4 + l4) ^ (d & 7) ^ ((d >> 3) & 7);
            const bf16x8_t vb = *(const bf16x8_t*)&Vts[d * 64 + cph * 8];
            o[mi][df] = __builtin_amdgcn_mfma_f32_16x16x32_bf16(pa, vb, o[mi][df], 0, 0, 0);
          }
        }
      }
    }
    __syncthreads(); // reads of Ks/Vts done before next tile's stage
  }

  if (!split) {
    #pragma unroll
    for (int mi = 0; mi < 2; mi++) {
      #pragma unroll
      for (int r = 0; r < 4; r++) {
        const float inv = 1.0f / lrun[mi][r];
        const size_t row = (size_t)bI * SEQ + qrow0 + mi * 16 + l4 * 4 + r;
        #pragma unroll
        for (int df = 0; df < 8; df++)
          attnb[row * D_MODEL + h * HDIM + df * 16 + l15] = f2bf(o[mi][df][r] * inv);
      }
    }
  } else {
    const int sl = bh * 8 + (qt - 8);
    #pragma unroll
    for (int mi = 0; mi < 2; mi++) {
      #pragma unroll
      for (int r = 0; r < 4; r++) {
        const int pr = w * 32 + mi * 16 + l4 * 4 + r;
        if (l15 == 0) {
          ml[sl * 512 + ch * 256 + pr] = mrun[mi][r];
          ml[sl * 512 + ch * 256 + 128 + pr] = lrun[mi][r];
        }
        if (ch == 0) {
          const size_t row = (size_t)bI * SEQ + qb + pr;
          #pragma unroll
          for (int df = 0; df < 8; df++)
            attnb[row * D_MODEL + h * HDIM + df * 16 + l15] = f2bf(o[mi][df][r]);
        } else {
          #pragma unroll
          for (int df = 0; df < 8; df++)
            o_part[(size_t)sl * 16384 + pr * 128 + df * 16 + l15] = f2bf(o[mi][df][r]);
        }
      }
    }
  }
}

extern "C" void kernel_launch(void* const* d_in, const int* in_sizes, int n_in,
                              void* d_out, int out_size, void* d_ws, size_t ws_size,
                              hipStream_t stream) {
  (void)in_sizes; (void)n_in; (void)out_size; (void)ws_size;
  const float* layer_input = (const float*)d_in[0];
  // d_in[1] = positions (unused by reference)
  const float* ln_in_w  = (const float*)d_in[2];
  const float* ln_in_b  = (const float*)d_in[3];
  const float* W_uvqk   = (const float*)d_in[4];
  const float* b_uvqk   = (const float*)d_in[5];
  const float* ln_out_w = (const float*)d_in[6];
  const float* ln_out_b = (const float*)d_in[7];
  const float* W_proj   = (const float*)d_in[8];
  const float* rms_w    = (const float*)d_in[9];
  const float* W1       = (const float*)d_in[10];
  const float* W2       = (const float*)d_in[11];
  float* out = (float*)d_out;

  char* ws = (char*)d_ws;
  u16* buf0    = (u16*)(ws);                          // 16 MB: normed/gated/ffn_in
  u16* mixed   = (u16*)(ws + ((size_t)16 << 20));     // 64 MB: uvqk out; later g
  u16* attnb   = (u16*)(ws + ((size_t)80 << 20));     // 16 MB
  u16* lout16  = (u16*)(ws + ((size_t)96 << 20));     // 16 MB: layer_output bf16 (post-attn)
  u16* Kc      = (u16*)(ws + ((size_t)96 << 20));     // 16 MB dense K (dead before proj)
  u16* Vtc     = (u16*)(ws + ((size_t)112 << 20));    // 16 MB dense V^T tiles (dead before proj)
  u16* wt_uvqk = (u16*)(ws + ((size_t)128 << 20));    // 8 MB
  u16* wt_proj = (u16*)(ws + ((size_t)136 << 20));    // 2 MB
  u16* wt_1    = (u16*)(ws + ((size_t)138 << 20));    // 4 MB (16-col-interleaved)
  u16* wt_2    = (u16*)(ws + ((size_t)142 << 20));    // 2 MB
  // split-K scratch lives in d_out (fully overwritten by the final GEMM):
  u16* o_part  = (u16*)d_out;                          // 8 MB partials (256 slots x 32KB)
  float* ml    = (float*)((char*)d_out + ((size_t)20 << 20)); // 512 KB m/l

  k_wconv<0><<<dim3(128, 32), 256, 0, stream>>>(W_uvqk, wt_uvqk, 1024, 4096);
  k_wconv<0><<<dim3(32, 32), 256, 0, stream>>>(W_proj, wt_proj, 1024, 1024);
  k_wconv<1><<<dim3(64, 32), 256, 0, stream>>>(W1, wt_1, 1024, 2048);
  k_wconv<0><<<dim3(32, 32), 256, 0, stream>>>(W2, wt_2, 1024, 1024);

  k_ln_in<<<NROWS, 256, 0, stream>>>(layer_input, ln_in_w, ln_in_b, buf0);
  k_gemm<EPI_UVQK><<<dim3(64, 32), 256, 0, stream>>>(buf0, wt_uvqk, mixed, b_uvqk, nullptr, Kc, Vtc, NROWS, 4096, 1024);
  k_attn<<<768, 256, 0, stream>>>(mixed, Kc, Vtc, attnb, o_part, ml);
  k_gated<<<NROWS, 256, 0, stream>>>(attnb, mixed, ln_out_w, ln_out_b, o_part, ml, buf0);
  k_gemm<EPI_BF16O><<<dim3(64, 8), 256, 0, stream>>>(buf0, wt_proj, lout16, nullptr, nullptr, nullptr, nullptr, NROWS, 1024, 1024);
  k_rms<<<NROWS, 256, 0, stream>>>(lout16, layer_input, rms_w, buf0);
  k_gemm<EPI_SILUMUL><<<dim3(64, 16), 256, 0, stream>>>(buf0, wt_1, mixed, nullptr, nullptr, nullptr, nullptr, NROWS, 2048, 1024);
  k_gemm<EPI_ADD_BF16><<<dim3(64, 8), 256, 0, stream>>>(mixed, wt_2, out, nullptr, nullptr, lout16, nullptr, NROWS, 1024, 1024);
}

// Round 25
// 340.045 us; speedup vs baseline: 1.1847x; 1.0266x over previous
//
#include <hip/hip_runtime.h>
#include <stdint.h>

typedef unsigned short u16;
typedef __bf16 bf16x8_t __attribute__((ext_vector_type(8)));
typedef float f32x4_t __attribute__((ext_vector_type(4)));

#define D_MODEL 1024
#define SEQ 2048
#define BATCH 4
#define NROWS (BATCH * SEQ)
#define HDIM 128

constexpr int EPI_UVQK = 0;    // silu+bias; route user/Q->mixed, V->Vtc, K->Kc
constexpr int EPI_BF16O = 1;   // proj: layer_output as bf16
constexpr int EPI_SILUMUL = 2; // interleaved W1: g = silu(a)*b directly
constexpr int EPI_ADD_BF16 = 3;// W2: out = acc + bf2f(addsrc16) (fp32 out)

__device__ __forceinline__ float bf2f(u16 u) {
  union { unsigned int i; float f; } v; v.i = ((unsigned int)u) << 16; return v.f;
}
__device__ __forceinline__ u16 f2bf(float f) {
  union { float f; unsigned int i; } v; v.f = f;
  unsigned int r = (v.i + 0x7FFFu + ((v.i >> 16) & 1u)) >> 16;
  return (u16)r;
}
__device__ __forceinline__ float silu_f(float x) { return x / (1.0f + __expf(-x)); }

// async global->LDS, 16B per lane. LDS dest must be wave-uniform base (HW adds lane*16).
__device__ __forceinline__ void load_lds16(const void* g, void* l) {
  auto gp = (const __attribute__((address_space(1))) char*)(uintptr_t)g;
  auto lp = (__attribute__((address_space(3))) char*)(uint32_t)(uintptr_t)l;
  __builtin_amdgcn_global_load_lds(gp, lp, 16, 0, 0);
}

__device__ __forceinline__ void block_sum2(float& a, float& b, float* sm) {
  #pragma unroll
  for (int off = 32; off > 0; off >>= 1) {
    a += __shfl_xor(a, off, 64);
    b += __shfl_xor(b, off, 64);
  }
  const int w = threadIdx.x >> 6;
  if ((threadIdx.x & 63) == 0) { sm[w] = a; sm[4 + w] = b; }
  __syncthreads();
  a = sm[0] + sm[1] + sm[2] + sm[3];
  b = sm[4] + sm[5] + sm[6] + sm[7];
}

// ---------------- fused prep: input LN (blocks 0..8191) + 4 weight transposes ----
// All five sub-tasks are mutually independent; merging removes 4 serial launch
// overheads and overlaps LN traffic with weight-conversion traffic.
// W1 (ILV path): 16-col-group interleave so silu(a)*b pairs share a lane.
__global__ __launch_bounds__(256)
void k_prep(const float* __restrict__ X, const float* __restrict__ lnw,
            const float* __restrict__ lnb, u16* __restrict__ Y,
            const float* __restrict__ Wu, u16* __restrict__ Wtu,
            const float* __restrict__ Wp, u16* __restrict__ Wtp,
            const float* __restrict__ W1s, u16* __restrict__ Wt1,
            const float* __restrict__ W2s, u16* __restrict__ Wt2) {
  __shared__ float tile[32][33];
  __shared__ float sm[8];
  const int b = blockIdx.x, t = threadIdx.x;
  if (b < NROWS) {
    // ---- input layernorm row b: fp32 -> bf16 ----
    const float4 v = ((const float4*)(X + (size_t)b * D_MODEL))[t];
    float s = v.x + v.y + v.z + v.w;
    float ss = v.x * v.x + v.y * v.y + v.z * v.z + v.w * v.w;
    block_sum2(s, ss, sm);
    const float mu = s * (1.0f / D_MODEL);
    const float var = ss * (1.0f / D_MODEL) - mu * mu;
    const float rs = rsqrtf(var + 1e-5f);
    const float4 wv = ((const float4*)lnw)[t];
    const float4 bv = ((const float4*)lnb)[t];
    ushort4 o;
    o.x = f2bf((v.x - mu) * rs * wv.x + bv.x);
    o.y = f2bf((v.y - mu) * rs * wv.y + bv.y);
    o.z = f2bf((v.z - mu) * rs * wv.z + bv.z);
    o.w = f2bf((v.w - mu) * rs * wv.w + bv.w);
    ((ushort4*)(Y + (size_t)b * D_MODEL))[t] = o;
  } else {
    // ---- weight transpose fp32 [K=1024][N] -> bf16 [N][K] ----
    int wb = b - NROWS;
    const float* W; u16* Wt; int N, nbx, ilv = 0;
    if (wb < 4096)       { W = Wu;  Wt = Wtu; N = 4096; nbx = 128; }
    else if (wb < 5120)  { wb -= 4096; W = Wp;  Wt = Wtp; N = 1024; nbx = 32; }
    else if (wb < 7168)  { wb -= 5120; W = W1s; Wt = Wt1; N = 2048; nbx = 64; ilv = 1; }
    else                 { wb -= 7168; W = W2s; Wt = Wt2; N = 1024; nbx = 32; }
    const int n0 = (wb % nbx) * 32, k0 = (wb / nbx) * 32;
    const int tx = t & 31, ty = t >> 5;
    #pragma unroll
    for (int i = 0; i < 4; i++)
      tile[ty + 8 * i][tx] = W[(size_t)(k0 + ty + 8 * i) * N + n0 + tx];
    __syncthreads();
    #pragma unroll
    for (int i = 0; i < 4; i++) {
      const int nlog = n0 + ty + 8 * i;
      int rowp;
      if (!ilv) rowp = nlog;
      else rowp = (nlog < 1024) ? (32 * (nlog >> 4) + (nlog & 15))
                                : (32 * ((nlog - 1024) >> 4) + 16 + ((nlog - 1024) & 15));
      Wt[(size_t)rowp * 1024 + k0 + tx] = f2bf(tile[tx][ty + 8 * i]);
    }
  }
}

// ---------------- parallel = user * layernorm(merged attn) ----------------
// Fuses the split-K combine: for seq>=1024 rows, merge ch0 (attnb, unnorm)
// with ch1 (o_part) using (m,l) in fp32 BEFORE the LN stats.
__global__ __launch_bounds__(256)
void k_gated(const u16* __restrict__ attn, const u16* __restrict__ mixed,
             const float* __restrict__ w, const float* __restrict__ b,
             const u16* __restrict__ o_part, const float* __restrict__ ml,
             u16* __restrict__ out) {
  __shared__ float sm[8];
  const int row = blockIdx.x, t = threadIdx.x;
  const int bI = row >> 11, seq = row & 2047;
  const ushort4 av = ((const ushort4*)(attn + (size_t)row * D_MODEL))[t];
  float x0, x1, x2, x3;
  if (seq < 1024) {
    x0 = bf2f(av.x); x1 = bf2f(av.y); x2 = bf2f(av.z); x3 = bf2f(av.w);
  } else {
    const int qti = (seq >> 7) - 8, pr = seq & 127;
    const int h = t >> 5;
    const int sl = (bI * 8 + h) * 8 + qti;
    const float m0 = ml[sl * 512 + pr];
    const float l0 = ml[sl * 512 + 128 + pr];
    const float m1 = ml[sl * 512 + 256 + pr];
    const float l1 = ml[sl * 512 + 384 + pr];
    const float M = fmaxf(m0, m1);
    const float w0 = __expf(m0 - M), w1 = __expf(m1 - M);
    const float inv = 1.0f / (w0 * l0 + w1 * l1);
    const float c0 = w0 * inv, c1 = w1 * inv;
    const ushort4 bv4 = *(const ushort4*)&o_part[(size_t)sl * 16384 + pr * 128 + ((4 * t) & 127)];
    x0 = c0 * bf2f(av.x) + c1 * bf2f(bv4.x);
    x1 = c0 * bf2f(av.y) + c1 * bf2f(bv4.y);
    x2 = c0 * bf2f(av.z) + c1 * bf2f(bv4.z);
    x3 = c0 * bf2f(av.w) + c1 * bf2f(bv4.w);
  }
  float s = x0 + x1 + x2 + x3;
  float ss = x0 * x0 + x1 * x1 + x2 * x2 + x3 * x3;
  block_sum2(s, ss, sm);
  const float mu = s * (1.0f / D_MODEL);
  const float rs = rsqrtf(ss * (1.0f / D_MODEL) - mu * mu + 1e-5f);
  const ushort4 uv = ((const ushort4*)(mixed + (size_t)row * 4096))[t]; // user = cols 0..1023
  const float4 wv = ((const float4*)w)[t];
  const float4 bv = ((const float4*)b)[t];
  ushort4 o;
  o.x = f2bf(bf2f(uv.x) * ((x0 - mu) * rs * wv.x + bv.x));
  o.y = f2bf(bf2f(uv.y) * ((x1 - mu) * rs * wv.y + bv.y));
  o.z = f2bf(bf2f(uv.z) * ((x2 - mu) * rs * wv.z + bv.z));
  o.w = f2bf(bf2f(uv.w) * ((x3 - mu) * rs * wv.w + bv.w));
  ((ushort4*)(out + (size_t)row * D_MODEL))[t] = o;
}

// ---------------- ffn_in = rmsnorm(layer_output(bf16) + layer_input) ----------------
__global__ __launch_bounds__(256)
void k_rms(const u16* __restrict__ lo, const float* __restrict__ li,
           const float* __restrict__ w, u16* __restrict__ out) {
  __shared__ float sm[8];
  const int row = blockIdx.x, t = threadIdx.x;
  const ushort4 a = ((const ushort4*)(lo + (size_t)row * D_MODEL))[t];
  const float4 bq = ((const float4*)(li + (size_t)row * D_MODEL))[t];
  const float x0 = bf2f(a.x) + bq.x, x1 = bf2f(a.y) + bq.y;
  const float x2 = bf2f(a.z) + bq.z, x3 = bf2f(a.w) + bq.w;
  float ss = x0 * x0 + x1 * x1 + x2 * x2 + x3 * x3, dummy = 0.f;
  block_sum2(ss, dummy, sm);
  const float rs = rsqrtf(ss * (1.0f / D_MODEL) + 1e-5f);
  const float4 wv = ((const float4*)w)[t];
  ushort4 o;
  o.x = f2bf(x0 * rs * wv.x);
  o.y = f2bf(x1 * rs * wv.y);
  o.z = f2bf(x2 * rs * wv.z);
  o.w = f2bf(x3 * rs * wv.w);
  ((ushort4*)(out + (size_t)row * D_MODEL))[t] = o;
}

// ---------------- GEMM: C[M,N] = A[M,K] @ Bt[N,K]^T, bf16 in, fp32 acc ----------------
// Baseline block mapping (R19/R21-verified; XCD remap hurts here, R20).
// EPI_UVQK: fused qkvprep. EPI_SILUMUL: fused silu-mul (interleaved wt_1).
// EPI_BF16O: bf16 layer_output. EPI_ADD_BF16: out = acc + bf2f(addsrc16[kc]).
template <int EPI>
__global__ __launch_bounds__(256, 2)
void k_gemm(const u16* __restrict__ A, const u16* __restrict__ Bt,
            void* __restrict__ Cout, const float* __restrict__ bias,
            const float* __restrict__ addsrc,
            u16* __restrict__ kc, u16* __restrict__ vtc,
            int M, int N, int K) {
  __shared__ u16 As[128 * 64];
  __shared__ u16 Bs[128 * 64];
  const int t = threadIdx.x, lane = t & 63, w = t >> 6;
  const int l15 = lane & 15, l4 = lane >> 4;
  const int wr = w >> 1, wc = w & 1;
  const int m0 = blockIdx.x * 128, n0 = blockIdx.y * 128;
  const int lr = lane >> 3, lc = lane & 7;
  const int swz = (lc ^ lr) * 8; // pre-swizzled global k-offset (elements)

  f32x4_t acc[4][4];
  #pragma unroll
  for (int mi = 0; mi < 4; mi++)
    #pragma unroll
    for (int ni = 0; ni < 4; ni++) {
      acc[mi][ni][0] = 0.f; acc[mi][ni][1] = 0.f; acc[mi][ni][2] = 0.f; acc[mi][ni][3] = 0.f;
    }

  const u16* Ab = A + (size_t)m0 * K + swz;
  const u16* Bb = Bt + (size_t)n0 * K + swz;

  for (int kt = 0; kt < K; kt += 64) {
    #pragma unroll
    for (int j = 0; j < 4; j++) {
      const size_t rr = (size_t)((w * 4 + j) * 8 + lr);
      load_lds16(Ab + rr * K + kt, &As[(w * 4 + j) * 512]);
      load_lds16(Bb + rr * K + kt, &Bs[(w * 4 + j) * 512]);
    }
    __syncthreads();
    #pragma unroll
    for (int kk = 0; kk < 2; kk++) {
      bf16x8_t af[4], bf[4];
      #pragma unroll
      for (int mi = 0; mi < 4; mi++) {
        const int row = wr * 64 + mi * 16 + l15;
        const int cph = (kk * 4 + l4) ^ (row & 7);
        af[mi] = *(const bf16x8_t*)&As[row * 64 + cph * 8];
      }
      #pragma unroll
      for (int ni = 0; ni < 4; ni++) {
        const int row = wc * 64 + ni * 16 + l15;
        const int cph = (kk * 4 + l4) ^ (row & 7);
        bf[ni] = *(const bf16x8_t*)&Bs[row * 64 + cph * 8];
      }
      #pragma unroll
      for (int mi = 0; mi < 4; mi++)
        #pragma unroll
        for (int ni = 0; ni < 4; ni++)
          acc[mi][ni] = __builtin_amdgcn_mfma_f32_16x16x32_bf16(af[mi], bf[ni], acc[mi][ni], 0, 0, 0);
    }
    __syncthreads();
  }

  if constexpr (EPI == EPI_SILUMUL) {
    // interleaved wt_1: acc[mi][2nj] = a-cols, acc[mi][2nj+1] = matching b-cols
    #pragma unroll
    for (int mi = 0; mi < 4; mi++)
      #pragma unroll
      for (int nj = 0; nj < 2; nj++) {
        const int gcol = (n0 >> 1) + wc * 32 + nj * 16 + l15;
        #pragma unroll
        for (int r = 0; r < 4; r++) {
          const size_t row = (size_t)(m0 + wr * 64 + mi * 16 + l4 * 4 + r);
          ((u16*)Cout)[row * 1024 + gcol] =
              f2bf(silu_f(acc[mi][2 * nj][r]) * acc[mi][2 * nj + 1][r]);
        }
      }
  } else {
    #pragma unroll
    for (int mi = 0; mi < 4; mi++) {
      #pragma unroll
      for (int ni = 0; ni < 4; ni++) {
        const int col = n0 + wc * 64 + ni * 16 + l15;
        float bv = 0.f;
        if constexpr (EPI == EPI_UVQK) bv = bias[col];
        if constexpr (EPI == EPI_UVQK) {
          const int rowb = m0 + wr * 64 + mi * 16 + l4 * 4; // 4-aligned base row
          u16 c4[4];
          #pragma unroll
          for (int r = 0; r < 4; r++) c4[r] = f2bf(silu_f(acc[mi][ni][r] + bv));
          if (col < 1024 || (col >= 2048 && col < 3072)) {
            #pragma unroll
            for (int r = 0; r < 4; r++)
              ((u16*)Cout)[(size_t)(rowb + r) * N + col] = c4[r];
          } else if (col < 2048) {
            const int h = (col - 1024) >> 7, d = (col - 1024) & 127;
            const int bI = rowb >> 11, seqr = rowb & 2047;
            const size_t off = ((size_t)(bI * 8 + h) * 32 + (seqr >> 6)) * 8192 + d * 64 + (seqr & 63);
            *(ushort4*)&vtc[off] = *(const ushort4*)c4;
          } else {
            const int h = (col - 3072) >> 7, d = (col - 3072) & 127;
            const int bI = rowb >> 11, seqr = rowb & 2047;
            #pragma unroll
            for (int r = 0; r < 4; r++)
              kc[((size_t)(bI * 8 + h) * 2048 + seqr + r) * 128 + d] = c4[r];
          }
        } else {
          #pragma unroll
          for (int r = 0; r < 4; r++) {
            const size_t row = (size_t)(m0 + wr * 64 + mi * 16 + l4 * 4 + r);
            float v = acc[mi][ni][r];
            if constexpr (EPI == EPI_BF16O) {
              ((u16*)Cout)[row * N + col] = f2bf(v);
            } else { // EPI_ADD_BF16: addsrc16 passed via kc
              ((float*)Cout)[row * N + col] = v + bf2f(kc[row * N + col]);
            }
          }
        }
      }
    }
  }
}

// ---------------- split-K flash attention (R15 body, XCD-clustered bh) ----------
// grid: flat 768 blocks. XCD remap: v=(f%8)*96+f/8 (bijective) so each XCD's
// 96 blocks cover 4 heads -> Kc/Vtc working set 4MB = one XCD L2.
__global__ __launch_bounds__(256, 2)
void k_attn(const u16* __restrict__ mixed, const u16* __restrict__ Kc,
            const u16* __restrict__ Vtc, u16* __restrict__ attnb,
            u16* __restrict__ o_part, float* __restrict__ ml) {
  __shared__ u16 Ks[64 * 128];   // [key][d], 16B-granule swizzled by key&7
  __shared__ u16 Vts[128 * 64];  // [d][key], swizzled by (d&7)^((d>>3)&7)
  __shared__ u16 Ps[4 * 16 * 64];// per-wave P half-tiles (8KB)
  const int t = threadIdx.x, lane = t & 63, w = t >> 6;
  const int l15 = lane & 15, l4 = lane >> 4;
  const int f = blockIdx.x;
  const int v = (f & 7) * 96 + (f >> 3);   // XCD-clustering bijection (768 = 8*96)
  const int ci = v % 24, bh = v / 24;
  const int bI = bh >> 3, h = bh & 7;
  int qt, ch;
  if (ci < 16) { qt = 15 - (ci >> 1); ch = ci & 1; }
  else { qt = 23 - ci; ch = 0; }
  const bool split = (qt >= 8);
  const int qb = qt * 128;
  const int nt_all = 2 * qt + 2;
  const int t0 = (split && ch == 1) ? (qt + 1) : 0;
  const int t1 = (split && ch == 0) ? (qt + 1) : nt_all;

  const u16* base = mixed + (size_t)bI * SEQ * 4096;
  const int qcol = 2 * D_MODEL + h * HDIM;
  const int qrow0 = qb + w * 32;
  const u16* Kh = Kc + (size_t)bh * SEQ * 128;
  const u16* Vh = Vtc + (size_t)bh * 32 * 8192;

  const int nk = lane;

  bf16x8_t qf[2][4];
  #pragma unroll
  for (int mi = 0; mi < 2; mi++) {
    const u16* qp = base + (size_t)(qrow0 + mi * 16 + l15) * 4096 + qcol + l4 * 8;
    #pragma unroll
    for (int ks = 0; ks < 4; ks++) qf[mi][ks] = *(const bf16x8_t*)(qp + ks * 32);
  }

  f32x4_t o[2][8];
  #pragma unroll
  for (int mi = 0; mi < 2; mi++)
    #pragma unroll
    for (int df = 0; df < 8; df++) { o[mi][df][0] = 0.f; o[mi][df][1] = 0.f; o[mi][df][2] = 0.f; o[mi][df][3] = 0.f; }
  float mrun[2][4], lrun[2][4];
  #pragma unroll
  for (int mi = 0; mi < 2; mi++)
    #pragma unroll
    for (int r = 0; r < 4; r++) { mrun[mi][r] = -1e30f; lrun[mi][r] = 0.f; }

  const float alpha = 0.08838834764831845f; // 1/sqrt(128)

  // ---- stage(tile): 8 global_load_lds per thread into single buffers ----
  auto stage = [&](int tile) {
    const u16* Kt = Kh + (size_t)(tile * 64) * 128;
    const u16* Vt = Vh + (size_t)tile * 8192;
    #pragma unroll
    for (int j = 0; j < 4; j++) {
      const int slot = j * 4 + w;
      const int kr = slot * 4 + (nk >> 4), gk = nk & 15;
      load_lds16(Kt + kr * 128 + ((gk ^ (kr & 7)) * 8), &Ks[slot * 512]);
      const int d = slot * 8 + (nk >> 3), gv = nk & 7;
      load_lds16(Vt + d * 64 + ((gv ^ (d & 7) ^ ((d >> 3) & 7)) * 8), &Vts[slot * 512]);
    }
  };

  for (int it = t0; it < t1; it++) {
    const int kb = it * 64;
    stage(it);
    __syncthreads(); // drain stage — covered by other resident blocks

    const bool active = (kb <= qrow0 + 31);
    const bool needmask = (kb + 63 > qrow0);
    if (active) {
      f32x4_t s[2][4];
      #pragma unroll
      for (int mi = 0; mi < 2; mi++)
        #pragma unroll
        for (int ni = 0; ni < 4; ni++) { s[mi][ni][0] = 0.f; s[mi][ni][1] = 0.f; s[mi][ni][2] = 0.f; s[mi][ni][3] = 0.f; }
      #pragma unroll
      for (int ks = 0; ks < 4; ks++) {
        bf16x8_t kf[4];
        #pragma unroll
        for (int ni = 0; ni < 4; ni++) {
          const int key = ni * 16 + l15;
          const int cph = (ks * 4 + l4) ^ (key & 7);
          kf[ni] = *(const bf16x8_t*)&Ks[key * 128 + cph * 8];
        }
        #pragma unroll
        for (int mi = 0; mi < 2; mi++)
          #pragma unroll
          for (int ni = 0; ni < 4; ni++)
            s[mi][ni] = __builtin_amdgcn_mfma_f32_16x16x32_bf16(qf[mi][ks], kf[ni], s[mi][ni], 0, 0, 0);
      }
      #pragma unroll
      for (int mi = 0; mi < 2; mi++) {
        #pragma unroll
        for (int r = 0; r < 4; r++) {
          const int qr = qrow0 + mi * 16 + l4 * 4 + r;
          float mx = -1e30f;
          #pragma unroll
          for (int ni = 0; ni < 4; ni++) {
            float v2 = s[mi][ni][r] * alpha;
            if (needmask) {
              const int key = kb + ni * 16 + l15;
              if (key > qr) v2 = -1e30f;
            }
            s[mi][ni][r] = v2;
            mx = fmaxf(mx, v2);
          }
          #pragma unroll
          for (int off = 1; off < 16; off <<= 1) mx = fmaxf(mx, __shfl_xor(mx, off, 64));
          const float mnew = fmaxf(mrun[mi][r], mx);
          const float fsc = __expf(mrun[mi][r] - mnew);
          mrun[mi][r] = mnew;
          lrun[mi][r] *= fsc;
          #pragma unroll
          for (int df = 0; df < 8; df++) o[mi][df][r] *= fsc;
          float ls = 0.f;
          #pragma unroll
          for (int ni = 0; ni < 4; ni++) {
            const float p = __expf(s[mi][ni][r] - mnew);
            s[mi][ni][r] = p;
            ls += p;
          }
          #pragma unroll
          for (int off = 1; off < 16; off <<= 1) ls += __shfl_xor(ls, off, 64);
          lrun[mi][r] += ls;
        }
        // P half-tile write (per-wave private region; wave-local ordering)
        #pragma unroll
        for (int ni = 0; ni < 4; ni++)
          #pragma unroll
          for (int r = 0; r < 4; r++) {
            const int pr = l4 * 4 + r;
            const int pc = ni * 16 + l15;
            Ps[w * 1024 + pr * 64 + (((pc >> 3) ^ (pr & 7)) * 8) + (pc & 7)] = f2bf(s[mi][ni][r]);
          }
        // PV for this half
        #pragma unroll
        for (int ks2 = 0; ks2 < 2; ks2++) {
          bf16x8_t pa;
          {
            const int pr = l15;
            const int cph = (ks2 * 4 + l4) ^ (pr & 7);
            pa = *(const bf16x8_t*)&Ps[w * 1024 + pr * 64 + cph * 8];
          }
          #pragma unroll
          for (int df = 0; df < 8; df++) {
            const int d = df * 16 + l15;
            const int cph = (ks2 * 4 + l4) ^ (d & 7) ^ ((d >> 3) & 7);
            const bf16x8_t vb = *(const bf16x8_t*)&Vts[d * 64 + cph * 8];
            o[mi][df] = __builtin_amdgcn_mfma_f32_16x16x32_bf16(pa, vb, o[mi][df], 0, 0, 0);
          }
        }
      }
    }
    __syncthreads(); // reads of Ks/Vts done before next tile's stage
  }

  if (!split) {
    #pragma unroll
    for (int mi = 0; mi < 2; mi++) {
      #pragma unroll
      for (int r = 0; r < 4; r++) {
        const float inv = 1.0f / lrun[mi][r];
        const size_t row = (size_t)bI * SEQ + qrow0 + mi * 16 + l4 * 4 + r;
        #pragma unroll
        for (int df = 0; df < 8; df++)
          attnb[row * D_MODEL + h * HDIM + df * 16 + l15] = f2bf(o[mi][df][r] * inv);
      }
    }
  } else {
    const int sl = bh * 8 + (qt - 8);
    #pragma unroll
    for (int mi = 0; mi < 2; mi++) {
      #pragma unroll
      for (int r = 0; r < 4; r++) {
        const int pr = w * 32 + mi * 16 + l4 * 4 + r;
        if (l15 == 0) {
          ml[sl * 512 + ch * 256 + pr] = mrun[mi][r];
          ml[sl * 512 + ch * 256 + 128 + pr] = lrun[mi][r];
        }
        if (ch == 0) {
          const size_t row = (size_t)bI * SEQ + qb + pr;
          #pragma unroll
          for (int df = 0; df < 8; df++)
            attnb[row * D_MODEL + h * HDIM + df * 16 + l15] = f2bf(o[mi][df][r]);
        } else {
          #pragma unroll
          for (int df = 0; df < 8; df++)
            o_part[(size_t)sl * 16384 + pr * 128 + df * 16 + l15] = f2bf(o[mi][df][r]);
        }
      }
    }
  }
}

extern "C" void kernel_launch(void* const* d_in, const int* in_sizes, int n_in,
                              void* d_out, int out_size, void* d_ws, size_t ws_size,
                              hipStream_t stream) {
  (void)in_sizes; (void)n_in; (void)out_size; (void)ws_size;
  const float* layer_input = (const float*)d_in[0];
  // d_in[1] = positions (unused by reference)
  const float* ln_in_w  = (const float*)d_in[2];
  const float* ln_in_b  = (const float*)d_in[3];
  const float* W_uvqk   = (const float*)d_in[4];
  const float* b_uvqk   = (const float*)d_in[5];
  const float* ln_out_w = (const float*)d_in[6];
  const float* ln_out_b = (const float*)d_in[7];
  const float* W_proj   = (const float*)d_in[8];
  const float* rms_w    = (const float*)d_in[9];
  const float* W1       = (const float*)d_in[10];
  const float* W2       = (const float*)d_in[11];
  float* out = (float*)d_out;

  char* ws = (char*)d_ws;
  u16* buf0    = (u16*)(ws);                          // 16 MB: normed/gated/ffn_in
  u16* mixed   = (u16*)(ws + ((size_t)16 << 20));     // 64 MB: uvqk out; later g
  u16* attnb   = (u16*)(ws + ((size_t)80 << 20));     // 16 MB
  u16* lout16  = (u16*)(ws + ((size_t)96 << 20));     // 16 MB: layer_output bf16 (post-attn)
  u16* Kc      = (u16*)(ws + ((size_t)96 << 20));     // 16 MB dense K (dead before proj)
  u16* Vtc     = (u16*)(ws + ((size_t)112 << 20));    // 16 MB dense V^T tiles (dead before proj)
  u16* wt_uvqk = (u16*)(ws + ((size_t)128 << 20));    // 8 MB
  u16* wt_proj = (u16*)(ws + ((size_t)136 << 20));    // 2 MB
  u16* wt_1    = (u16*)(ws + ((size_t)138 << 20));    // 4 MB (16-col-interleaved)
  u16* wt_2    = (u16*)(ws + ((size_t)142 << 20));    // 2 MB
  // split-K scratch lives in d_out (fully overwritten by the final GEMM):
  u16* o_part  = (u16*)d_out;                          // 8 MB partials (256 slots x 32KB)
  float* ml    = (float*)((char*)d_out + ((size_t)20 << 20)); // 512 KB m/l

  k_prep<<<NROWS + 8192, 256, 0, stream>>>(layer_input, ln_in_w, ln_in_b, buf0,
                                           W_uvqk, wt_uvqk, W_proj, wt_proj,
                                           W1, wt_1, W2, wt_2);
  k_gemm<EPI_UVQK><<<dim3(64, 32), 256, 0, stream>>>(buf0, wt_uvqk, mixed, b_uvqk, nullptr, Kc, Vtc, NROWS, 4096, 1024);
  k_attn<<<768, 256, 0, stream>>>(mixed, Kc, Vtc, attnb, o_part, ml);
  k_gated<<<NROWS, 256, 0, stream>>>(attnb, mixed, ln_out_w, ln_out_b, o_part, ml, buf0);
  k_gemm<EPI_BF16O><<<dim3(64, 8), 256, 0, stream>>>(buf0, wt_proj, lout16, nullptr, nullptr, nullptr, nullptr, NROWS, 1024, 1024);
  k_rms<<<NROWS, 256, 0, stream>>>(lout16, layer_input, rms_w, buf0);
  k_gemm<EPI_SILUMUL><<<dim3(64, 16), 256, 0, stream>>>(buf0, wt_1, mixed, nullptr, nullptr, nullptr, nullptr, NROWS, 2048, 1024);
  k_gemm<EPI_ADD_BF16><<<dim3(64, 8), 256, 0, stream>>>(mixed, wt_2, out, nullptr, nullptr, lout16, nullptr, NROWS, 1024, 1024);
}